// Round 1
// baseline (720.931 us; speedup 1.0000x reference)
//
#include <hip/hip_runtime.h>

typedef __attribute__((ext_vector_type(8))) short bf16x8;
typedef __attribute__((ext_vector_type(4))) short bf16x4;
typedef __attribute__((ext_vector_type(4))) float f32x4;
typedef __attribute__((ext_vector_type(4))) unsigned int u32x4;

#define DEV static __device__ __forceinline__

DEV short f2bf(float f) {
  union { float f; unsigned u; } v; v.f = f;
  unsigned r = v.u + 0x7fffu + ((v.u >> 16) & 1u);
  return (short)(r >> 16);
}
DEV unsigned pack2(float lo, float hi) {
  return ((unsigned)(unsigned short)f2bf(hi) << 16) | (unsigned)(unsigned short)f2bf(lo);
}

// ---------------------------------------------------------------------------
// Weight cast+transpose: Wt[n*K + k] = bf16(W[k*N + n])
__global__ void tcast_kernel(const float* __restrict__ W, short* __restrict__ Wt,
                             int K, int N) {
  int o = blockIdx.x * 256 + threadIdx.x;
  int n = o / K, k = o - n * K;
  Wt[o] = f2bf(W[(size_t)k * N + n]);
}

// ---------------------------------------------------------------------------
// kvK = bf16(a+pe), kvV = bf16(a); 4 elems/thread, exact cover
__global__ void addpe_kernel(const float* __restrict__ a, const float* __restrict__ p,
                             short* __restrict__ outK, short* __restrict__ outV) {
  size_t i = (size_t)(blockIdx.x * 256 + threadIdx.x) * 4;
  f32x4 va = *(const f32x4*)(a + i);
  f32x4 vp = *(const f32x4*)(p + i);
  bf16x4 k, v;
#pragma unroll
  for (int j = 0; j < 4; j++) { k[j] = f2bf(va[j] + vp[j]); v[j] = f2bf(va[j]); }
  *(bf16x4*)(outK + i) = k;
  *(bf16x4*)(outV + i) = v;
}

// ---------------------------------------------------------------------------
// LayerNorm over D=512, one wave per row, optional +pe, bf16 out
template<int PE>
__global__ __launch_bounds__(256)
void ln_kernel(const float* __restrict__ X, const float* __restrict__ gamma,
               const float* __restrict__ beta, const float* __restrict__ pe,
               short* __restrict__ Y) {
  const int wave = threadIdx.x >> 6, lane = threadIdx.x & 63;
  const int row = blockIdx.x * 4 + wave;
  const float* x = X + (size_t)row * 512 + lane * 8;
  f32x4 v0 = *(const f32x4*)x;
  f32x4 v1 = *(const f32x4*)(x + 4);
  float s = ((v0[0] + v0[1]) + (v0[2] + v0[3])) + ((v1[0] + v1[1]) + (v1[2] + v1[3]));
#pragma unroll
  for (int m = 1; m < 64; m <<= 1) s += __shfl_xor(s, m);
  float mu = s * (1.0f / 512.0f);
  float vs = 0.0f;
#pragma unroll
  for (int j = 0; j < 4; j++) { float d = v0[j] - mu; vs += d * d; }
#pragma unroll
  for (int j = 0; j < 4; j++) { float d = v1[j] - mu; vs += d * d; }
#pragma unroll
  for (int m = 1; m < 64; m <<= 1) vs += __shfl_xor(vs, m);
  float rstd = rsqrtf(vs * (1.0f / 512.0f) + 1e-6f);
  const int c = lane * 8;
  f32x4 g0 = *(const f32x4*)(gamma + c);
  f32x4 g1 = *(const f32x4*)(gamma + c + 4);
  f32x4 b0 = *(const f32x4*)(beta + c);
  f32x4 b1 = *(const f32x4*)(beta + c + 4);
  f32x4 p0 = {0,0,0,0}, p1 = {0,0,0,0};
  if (PE) {
    p0 = *(const f32x4*)(pe + (size_t)row * 512 + c);
    p1 = *(const f32x4*)(pe + (size_t)row * 512 + c + 4);
  }
  bf16x8 out;
#pragma unroll
  for (int j = 0; j < 4; j++) out[j]     = f2bf((v0[j] - mu) * rstd * g0[j] + b0[j] + p0[j]);
#pragma unroll
  for (int j = 0; j < 4; j++) out[4 + j] = f2bf((v1[j] - mu) * rstd * g1[j] + b1[j] + p1[j]);
  *(bf16x8*)(Y + (size_t)row * 512 + c) = out;
}

// ---------------------------------------------------------------------------
// GEMM: C(M,N) = act(A(M,K)bf16 @ Wt(N,K)^T bf16 + bias) [+res, fp32 out]
// 64x64 tile, 4 waves (2x2), each wave 32x32 via 2x2 16x16x32 MFMA frags.
template<int OUTF32, int RELU>
__global__ __launch_bounds__(256)
void gemm_kernel(const short* __restrict__ A, const short* __restrict__ Bt,
                 const float* __restrict__ bias, const float* __restrict__ res,
                 void* __restrict__ Cv, int M, int N, int K) {
  const int lane = threadIdx.x & 63;
  const int wave = threadIdx.x >> 6;
  const int g = lane >> 4, x15 = lane & 15;
  const int wm = wave >> 1, wn = wave & 1;
  const int Mb = blockIdx.x * 64, Nb = blockIdx.y * 64;

  f32x4 acc[2][2] = {{{0,0,0,0},{0,0,0,0}},{{0,0,0,0},{0,0,0,0}}};
  const short* Arow = A + (size_t)(Mb + wm * 32 + x15) * K + g * 8;
  const short* Brow = Bt + (size_t)(Nb + wn * 32 + x15) * K + g * 8;
  for (int kk = 0; kk < K; kk += 32) {
    bf16x8 a0 = *(const bf16x8*)(Arow + kk);
    bf16x8 a1 = *(const bf16x8*)(Arow + (size_t)16 * K + kk);
    bf16x8 b0 = *(const bf16x8*)(Brow + kk);
    bf16x8 b1 = *(const bf16x8*)(Brow + (size_t)16 * K + kk);
    acc[0][0] = __builtin_amdgcn_mfma_f32_16x16x32_bf16(a0, b0, acc[0][0], 0, 0, 0);
    acc[0][1] = __builtin_amdgcn_mfma_f32_16x16x32_bf16(a0, b1, acc[0][1], 0, 0, 0);
    acc[1][0] = __builtin_amdgcn_mfma_f32_16x16x32_bf16(a1, b0, acc[1][0], 0, 0, 0);
    acc[1][1] = __builtin_amdgcn_mfma_f32_16x16x32_bf16(a1, b1, acc[1][1], 0, 0, 0);
  }
#pragma unroll
  for (int fm = 0; fm < 2; fm++)
#pragma unroll
    for (int fn = 0; fn < 2; fn++) {
      int n = Nb + wn * 32 + fn * 16 + x15;
      float bs = bias[n];
#pragma unroll
      for (int r = 0; r < 4; r++) {
        int m = Mb + wm * 32 + fm * 16 + g * 4 + r;
        float v = acc[fm][fn][r] + bs;
        if (RELU) v = fmaxf(v, 0.0f);
        if (OUTF32) {
          ((float*)Cv)[(size_t)m * N + n] = res[(size_t)m * N + n] + v;
        } else {
          ((short*)Cv)[(size_t)m * N + n] = f2bf(v);
        }
      }
    }
}

// ---------------------------------------------------------------------------
// Flash attention: B=2, Lq=1024, Lk=4096, D=512, H=8, dh=64, scale=1/8.
// 1 wave per (b,h,16 q-rows). Swapped QK^T (S^T in C-layout), in-reg softmax,
// PV via 16x16x32 with quad-exchange of P across lanes.
__global__ __launch_bounds__(64)
void attn_kernel(const short* __restrict__ Q, const short* __restrict__ K,
                 const short* __restrict__ V, short* __restrict__ O) {
  const int lane = threadIdx.x;
  const int g = lane >> 4, q = lane & 15;
  const int qt = blockIdx.x & 63;
  const int h = (blockIdx.x >> 6) & 7;
  const int b = blockIdx.x >> 9;
  const short* Qp = Q + ((size_t)b * 1024 + qt * 16) * 512 + h * 64;
  const short* Kp = K + (size_t)b * 4096 * 512 + h * 64;
  const short* Vp = V + (size_t)b * 4096 * 512 + h * 64;

  // Q as B-operand frags: lane holds Q[q][g*8+j] (k-halves 0..31, 32..63)
  bf16x8 qf0 = *(const bf16x8*)(Qp + (size_t)q * 512 + g * 8);
  bf16x8 qf1 = *(const bf16x8*)(Qp + (size_t)q * 512 + 32 + g * 8);

  f32x4 acc[4] = {{0,0,0,0},{0,0,0,0},{0,0,0,0},{0,0,0,0}};
  float mrun = -1e30f, lsum = 0.0f;

  for (int kb = 0; kb < 4096; kb += 32) {
    // K as A-operand: keys kb+16f+q (f=0,1), kdims g*8 (+0/+32)
    const short* kp0 = Kp + (size_t)(kb + q) * 512 + g * 8;
    const short* kp1 = kp0 + (size_t)16 * 512;
    bf16x8 k00 = *(const bf16x8*)kp0;
    bf16x8 k01 = *(const bf16x8*)(kp0 + 32);
    bf16x8 k10 = *(const bf16x8*)kp1;
    bf16x8 k11 = *(const bf16x8*)(kp1 + 32);
    f32x4 s0 = {0,0,0,0}, s1 = {0,0,0,0};
    s0 = __builtin_amdgcn_mfma_f32_16x16x32_bf16(k00, qf0, s0, 0, 0, 0);
    s0 = __builtin_amdgcn_mfma_f32_16x16x32_bf16(k01, qf1, s0, 0, 0, 0);
    s1 = __builtin_amdgcn_mfma_f32_16x16x32_bf16(k10, qf0, s1, 0, 0, 0);
    s1 = __builtin_amdgcn_mfma_f32_16x16x32_bf16(k11, qf1, s1, 0, 0, 0);

    // S^T layout: sv[f*4+r] = score(q=lane&15, key = kb + 16f + 4g + r)
    float sv[8];
    float tmax = -1e30f;
#pragma unroll
    for (int r = 0; r < 4; r++) { sv[r] = s0[r] * 0.125f; tmax = fmaxf(tmax, sv[r]); }
#pragma unroll
    for (int r = 0; r < 4; r++) { sv[4 + r] = s1[r] * 0.125f; tmax = fmaxf(tmax, sv[4 + r]); }
    tmax = fmaxf(tmax, __shfl_xor(tmax, 16));
    tmax = fmaxf(tmax, __shfl_xor(tmax, 32));
    float mnew = fmaxf(mrun, tmax);
    float corr = __expf(mrun - mnew);
    float p[8], psum = 0.0f;
#pragma unroll
    for (int i = 0; i < 8; i++) { p[i] = __expf(sv[i] - mnew); psum += p[i]; }
    psum += __shfl_xor(psum, 16);
    psum += __shfl_xor(psum, 32);
    lsum = lsum * corr + psum;
    mrun = mnew;
#pragma unroll
    for (int df = 0; df < 4; df++)
#pragma unroll
      for (int r = 0; r < 4; r++) acc[df][r] *= corr;

    // pack P quads to bf16 words; quad(f,g) = keys {16f+4g..+3} for column q
    unsigned w00 = pack2(p[0], p[1]), w01 = pack2(p[2], p[3]);
    unsigned w10 = pack2(p[4], p[5]), w11 = pack2(p[6], p[7]);
    // exchange -> B-frag words for keys {8g..8g+7}, col q
    int src0 = (g & 1) * 32 + q;
    int src1 = src0 + 16;
    unsigned a0 = (unsigned)__shfl((int)w00, src0);
    unsigned a1 = (unsigned)__shfl((int)w01, src0);
    unsigned c0 = (unsigned)__shfl((int)w10, src0);
    unsigned c1 = (unsigned)__shfl((int)w11, src0);
    unsigned d0 = (unsigned)__shfl((int)w00, src1);
    unsigned d1 = (unsigned)__shfl((int)w01, src1);
    unsigned e0 = (unsigned)__shfl((int)w10, src1);
    unsigned e1 = (unsigned)__shfl((int)w11, src1);
    int fsel = g >> 1;
    u32x4 pw;
    pw[0] = fsel ? c0 : a0;
    pw[1] = fsel ? c1 : a1;
    pw[2] = fsel ? e0 : d0;
    pw[3] = fsel ? e1 : d1;
    bf16x8 pfrag = __builtin_bit_cast(bf16x8, pw);

    // PV: A = V^T frag: lane holds V[kb+g*8+j][df*16 + q]
    const short* vb = Vp + (size_t)(kb + g * 8) * 512 + q;
#pragma unroll
    for (int df = 0; df < 4; df++) {
      bf16x8 vf;
#pragma unroll
      for (int j = 0; j < 8; j++) vf[j] = vb[(size_t)j * 512 + df * 16];
      acc[df] = __builtin_amdgcn_mfma_f32_16x16x32_bf16(vf, pfrag, acc[df], 0, 0, 0);
    }
  }

  float inv = 1.0f / lsum;
  short* Op = O + ((size_t)b * 1024 + qt * 16 + q) * 512 + h * 64 + g * 4;
#pragma unroll
  for (int df = 0; df < 4; df++) {
    bf16x4 ov;
#pragma unroll
    for (int r = 0; r < 4; r++) ov[r] = f2bf(acc[df][r] * inv);
    *(bf16x4*)(Op + df * 16) = ov;
  }
}

// ---------------------------------------------------------------------------
extern "C" void kernel_launch(void* const* d_in, const int* in_sizes, int n_in,
                              void* d_out, int out_size, void* d_ws, size_t ws_size,
                              hipStream_t stream) {
  const int D = 512, F = 2048;
  const int Mq = 2048, Mkv = 8192;  // B*Lq, B*Lkv

  char* ws = (char*)d_ws;
  size_t off = 0;
  auto alloc = [&](size_t bytes) { char* p = ws + off; off += (bytes + 255) & ~(size_t)255; return p; };
  float* x    = (float*)alloc((size_t)Mq * D * 4);
  short* qln  = (short*)alloc((size_t)Mq * D * 2);
  short* kvK  = (short*)alloc((size_t)Mkv * D * 2);
  short* kvV  = (short*)alloc((size_t)Mkv * D * 2);
  short* Qb   = (short*)alloc((size_t)Mq * D * 2);
  short* Kb   = (short*)alloc((size_t)Mkv * D * 2);
  short* Vb   = (short*)alloc((size_t)Mkv * D * 2);
  short* attnb= (short*)alloc((size_t)Mq * D * 2);
  short* hffn = (short*)alloc((size_t)Mq * F * 2);
  short* WT[8];
  for (int i = 0; i < 8; i++) WT[i] = (short*)alloc((size_t)D * D * 2);
  short* w1T = (short*)alloc((size_t)D * F * 2);
  short* w2T = (short*)alloc((size_t)F * D * 2);

  // weights -> bf16 transposed
  auto TC = [&](int idx, short* dst, int K, int N) {
    tcast_kernel<<<(K * N) / 256, 256, 0, stream>>>((const float*)d_in[idx], dst, K, N);
  };
  TC(6, WT[0], D, D);  TC(7, WT[1], D, D);  TC(8, WT[2], D, D);  TC(9, WT[3], D, D);
  TC(16, WT[4], D, D); TC(17, WT[5], D, D); TC(18, WT[6], D, D); TC(19, WT[7], D, D);
  TC(26, w1T, D, F);
  TC(28, w2T, F, D);

  float* out = (float*)d_out;
  hipMemcpyAsync(x, d_in[0], (size_t)Mq * D * 4, hipMemcpyDeviceToDevice, stream);
  hipMemcpyAsync(out + (size_t)Mq * D, d_in[2], (size_t)Mkv * D * 4, hipMemcpyDeviceToDevice, stream);
  hipMemcpyAsync(out + (size_t)Mq * D + (size_t)Mkv * D, d_in[4], (size_t)Mkv * D * 4,
                 hipMemcpyDeviceToDevice, stream);

  auto sublayer = [&](int kv_idx, int pe_idx, int w0, int b0, int g_idx, int b_idx) {
    ln_kernel<1><<<Mq / 4, 256, 0, stream>>>(x, (const float*)d_in[g_idx],
                                             (const float*)d_in[b_idx],
                                             (const float*)d_in[1], qln);
    addpe_kernel<<<Mkv * D / 1024, 256, 0, stream>>>((const float*)d_in[kv_idx],
                                                     (const float*)d_in[pe_idx], kvK, kvV);
    gemm_kernel<0, 0><<<dim3(Mq / 64, D / 64), 256, 0, stream>>>(
        qln, WT[w0 - 6 < 8 ? (w0 == 6 ? 0 : 4) : 0] /*placeholder*/, nullptr, nullptr, nullptr, 0, 0, 0);
  };
  (void)sublayer;  // not used; explicit sequences below for clarity

  // ---- frame sublayer ----
  ln_kernel<1><<<Mq / 4, 256, 0, stream>>>(x, (const float*)d_in[14], (const float*)d_in[15],
                                           (const float*)d_in[1], qln);
  addpe_kernel<<<(Mkv * D) / 1024, 256, 0, stream>>>((const float*)d_in[2], (const float*)d_in[3],
                                                     kvK, kvV);
  gemm_kernel<0, 0><<<dim3(Mq / 64, D / 64), 256, 0, stream>>>(qln, WT[0], (const float*)d_in[10],
                                                               nullptr, Qb, Mq, D, D);
  gemm_kernel<0, 0><<<dim3(Mkv / 64, D / 64), 256, 0, stream>>>(kvK, WT[1], (const float*)d_in[11],
                                                                nullptr, Kb, Mkv, D, D);
  gemm_kernel<0, 0><<<dim3(Mkv / 64, D / 64), 256, 0, stream>>>(kvV, WT[2], (const float*)d_in[12],
                                                                nullptr, Vb, Mkv, D, D);
  attn_kernel<<<1024, 64, 0, stream>>>(Qb, Kb, Vb, attnb);
  gemm_kernel<1, 0><<<dim3(Mq / 64, D / 64), 256, 0, stream>>>(attnb, WT[3], (const float*)d_in[13],
                                                               x, x, Mq, D, D);

  // ---- obj sublayer ----
  ln_kernel<1><<<Mq / 4, 256, 0, stream>>>(x, (const float*)d_in[24], (const float*)d_in[25],
                                           (const float*)d_in[1], qln);
  addpe_kernel<<<(Mkv * D) / 1024, 256, 0, stream>>>((const float*)d_in[4], (const float*)d_in[5],
                                                     kvK, kvV);
  gemm_kernel<0, 0><<<dim3(Mq / 64, D / 64), 256, 0, stream>>>(qln, WT[4], (const float*)d_in[20],
                                                               nullptr, Qb, Mq, D, D);
  gemm_kernel<0, 0><<<dim3(Mkv / 64, D / 64), 256, 0, stream>>>(kvK, WT[5], (const float*)d_in[21],
                                                                nullptr, Kb, Mkv, D, D);
  gemm_kernel<0, 0><<<dim3(Mkv / 64, D / 64), 256, 0, stream>>>(kvV, WT[6], (const float*)d_in[22],
                                                                nullptr, Vb, Mkv, D, D);
  attn_kernel<<<1024, 64, 0, stream>>>(Qb, Kb, Vb, attnb);
  gemm_kernel<1, 0><<<dim3(Mq / 64, D / 64), 256, 0, stream>>>(attnb, WT[7], (const float*)d_in[23],
                                                               x, x, Mq, D, D);

  // ---- FFN sublayer ----
  ln_kernel<0><<<Mq / 4, 256, 0, stream>>>(x, (const float*)d_in[30], (const float*)d_in[31],
                                           nullptr, qln);
  gemm_kernel<0, 1><<<dim3(Mq / 64, F / 64), 256, 0, stream>>>(qln, w1T, (const float*)d_in[27],
                                                               nullptr, hffn, Mq, F, D);
  gemm_kernel<1, 0><<<dim3(Mq / 64, D / 64), 256, 0, stream>>>(hffn, w2T, (const float*)d_in[29],
                                                               x, out, Mq, D, F);
}

// Round 2
// 710.515 us; speedup vs baseline: 1.0147x; 1.0147x over previous
//
#include <hip/hip_runtime.h>

typedef __attribute__((ext_vector_type(8))) short bf16x8;
typedef __attribute__((ext_vector_type(4))) short bf16x4;
typedef __attribute__((ext_vector_type(4))) float f32x4;
typedef __attribute__((ext_vector_type(4))) unsigned int u32x4;

#define DEV static __device__ __forceinline__

DEV short f2bf(float f) {
  union { float f; unsigned u; } v; v.f = f;
  unsigned r = v.u + 0x7fffu + ((v.u >> 16) & 1u);
  return (short)(r >> 16);
}
DEV unsigned pack2(float lo, float hi) {
  return ((unsigned)(unsigned short)f2bf(hi) << 16) | (unsigned)(unsigned short)f2bf(lo);
}

// ---------------------------------------------------------------------------
// Fused weight cast+transpose for all 10 weights: Wt[n*K+k] = bf16(W[k*N+n])
struct TcArgs {
  const float* src[10];
  short* dst[10];
  int lk[10];   // log2(K)
  int ln[10];   // log2(N)
};
__global__ __launch_bounds__(256)
void tcast_all_kernel(TcArgs a) {
  const int w = blockIdx.y;
  const int o = blockIdx.x * 256 + threadIdx.x;
  const int lk = a.lk[w], ln = a.ln[w];
  if (o >= (1 << (lk + ln))) return;
  const int n = o >> lk, k = o & ((1 << lk) - 1);
  a.dst[w][o] = f2bf(a.src[w][((size_t)k << ln) + n]);
}

// ---------------------------------------------------------------------------
// kvK = bf16(a+pe), kvV = bf16(a); 4 elems/thread
__global__ __launch_bounds__(256)
void addpe_kernel(const float* __restrict__ a, const float* __restrict__ p,
                  short* __restrict__ outK, short* __restrict__ outV) {
  size_t i = (size_t)(blockIdx.x * 256 + threadIdx.x) * 4;
  f32x4 va = *(const f32x4*)(a + i);
  f32x4 vp = *(const f32x4*)(p + i);
  bf16x4 k, v;
#pragma unroll
  for (int j = 0; j < 4; j++) { k[j] = f2bf(va[j] + vp[j]); v[j] = f2bf(va[j]); }
  *(bf16x4*)(outK + i) = k;
  *(bf16x4*)(outV + i) = v;
}

// ---------------------------------------------------------------------------
// LayerNorm over D=512, one wave per row, optional +pe, bf16 out
template<int PE>
__global__ __launch_bounds__(256)
void ln_kernel(const float* __restrict__ X, const float* __restrict__ gamma,
               const float* __restrict__ beta, const float* __restrict__ pe,
               short* __restrict__ Y) {
  const int wave = threadIdx.x >> 6, lane = threadIdx.x & 63;
  const int row = blockIdx.x * 4 + wave;
  const float* x = X + (size_t)row * 512 + lane * 8;
  f32x4 v0 = *(const f32x4*)x;
  f32x4 v1 = *(const f32x4*)(x + 4);
  float s = ((v0[0] + v0[1]) + (v0[2] + v0[3])) + ((v1[0] + v1[1]) + (v1[2] + v1[3]));
#pragma unroll
  for (int m = 1; m < 64; m <<= 1) s += __shfl_xor(s, m);
  float mu = s * (1.0f / 512.0f);
  float vs = 0.0f;
#pragma unroll
  for (int j = 0; j < 4; j++) { float d = v0[j] - mu; vs += d * d; }
#pragma unroll
  for (int j = 0; j < 4; j++) { float d = v1[j] - mu; vs += d * d; }
#pragma unroll
  for (int m = 1; m < 64; m <<= 1) vs += __shfl_xor(vs, m);
  float rstd = rsqrtf(vs * (1.0f / 512.0f) + 1e-6f);
  const int c = lane * 8;
  f32x4 g0 = *(const f32x4*)(gamma + c);
  f32x4 g1 = *(const f32x4*)(gamma + c + 4);
  f32x4 b0 = *(const f32x4*)(beta + c);
  f32x4 b1 = *(const f32x4*)(beta + c + 4);
  f32x4 p0 = {0,0,0,0}, p1 = {0,0,0,0};
  if (PE) {
    p0 = *(const f32x4*)(pe + (size_t)row * 512 + c);
    p1 = *(const f32x4*)(pe + (size_t)row * 512 + c + 4);
  }
  bf16x8 out;
#pragma unroll
  for (int j = 0; j < 4; j++) out[j]     = f2bf((v0[j] - mu) * rstd * g0[j] + b0[j] + p0[j]);
#pragma unroll
  for (int j = 0; j < 4; j++) out[4 + j] = f2bf((v1[j] - mu) * rstd * g1[j] + b1[j] + p1[j]);
  *(bf16x8*)(Y + (size_t)row * 512 + c) = out;
}

// ---------------------------------------------------------------------------
// GEMM: C(M,N) = act(A(M,K)bf16 @ Wt(N,K)^T bf16 + bias)
// OUTMODE: 0 = bf16 row-major, 1 = f32 row-major + residual, 2 = bf16 V-transposed
//          (Vt[(b*8+h)*64 + d][4096], for attention PV fragments)
template<int OUTMODE, int RELU, int K>
__global__ __launch_bounds__(256)
void gemm_kernel(const short* __restrict__ A, const short* __restrict__ Bt,
                 const float* __restrict__ bias, const float* __restrict__ res,
                 void* __restrict__ Cv, int M, int N) {
  const int lane = threadIdx.x & 63;
  const int wave = threadIdx.x >> 6;
  const int g = lane >> 4, x15 = lane & 15;
  const int wm = wave >> 1, wn = wave & 1;
  const int Mb = blockIdx.x * 64, Nb = blockIdx.y * 64;

  f32x4 acc[2][2] = {{{0,0,0,0},{0,0,0,0}},{{0,0,0,0},{0,0,0,0}}};
  const short* Arow = A + (size_t)(Mb + wm * 32 + x15) * K + g * 8;
  const short* Brow = Bt + (size_t)(Nb + wn * 32 + x15) * K + g * 8;
#pragma unroll 4
  for (int kk = 0; kk < K; kk += 32) {
    bf16x8 a0 = *(const bf16x8*)(Arow + kk);
    bf16x8 a1 = *(const bf16x8*)(Arow + (size_t)16 * K + kk);
    bf16x8 b0 = *(const bf16x8*)(Brow + kk);
    bf16x8 b1 = *(const bf16x8*)(Brow + (size_t)16 * K + kk);
    acc[0][0] = __builtin_amdgcn_mfma_f32_16x16x32_bf16(a0, b0, acc[0][0], 0, 0, 0);
    acc[0][1] = __builtin_amdgcn_mfma_f32_16x16x32_bf16(a0, b1, acc[0][1], 0, 0, 0);
    acc[1][0] = __builtin_amdgcn_mfma_f32_16x16x32_bf16(a1, b0, acc[1][0], 0, 0, 0);
    acc[1][1] = __builtin_amdgcn_mfma_f32_16x16x32_bf16(a1, b1, acc[1][1], 0, 0, 0);
  }
#pragma unroll
  for (int fm = 0; fm < 2; fm++)
#pragma unroll
    for (int fn = 0; fn < 2; fn++) {
      int n = Nb + wn * 32 + fn * 16 + x15;
      float bs = bias[n];
      int m0 = Mb + wm * 32 + fm * 16 + g * 4;
      if (OUTMODE == 2) {
        // V-transposed: row = (b*8+h)*64 + (n&63), col = m within batch
        int bh = ((m0 >> 12) << 3) + (n >> 6);
        bf16x4 ov;
#pragma unroll
        for (int r = 0; r < 4; r++) ov[r] = f2bf(acc[fm][fn][r] + bs);
        *(bf16x4*)((short*)Cv + ((size_t)bh * 64 + (n & 63)) * 4096 + (m0 & 4095)) = ov;
      } else {
#pragma unroll
        for (int r = 0; r < 4; r++) {
          int m = m0 + r;
          float v = acc[fm][fn][r] + bs;
          if (RELU) v = fmaxf(v, 0.0f);
          if (OUTMODE == 1) {
            ((float*)Cv)[(size_t)m * N + n] = res[(size_t)m * N + n] + v;
          } else {
            ((short*)Cv)[(size_t)m * N + n] = f2bf(v);
          }
        }
      }
    }
}

// ---------------------------------------------------------------------------
// Flash attention, k-split x4. B=2, Lq=1024, Lk=4096, dh=64, H=8, scale=1/8.
// 1 wave per (ks, b, h, 16 q-rows); keys [ks*1024, ks*1024+1024).
// Swapped QK^T, in-reg online softmax w/ defer-max, PV from transposed V.
// Writes unnormalized partial O (f32) + (m, l) per q-row.
__global__ __launch_bounds__(64)
void attn_kernel(const short* __restrict__ Q, const short* __restrict__ K,
                 const short* __restrict__ Vt, float* __restrict__ Opart,
                 float2* __restrict__ ml) {
  const int lane = threadIdx.x;
  const int g = lane >> 4, q = lane & 15;
  const int ks = blockIdx.x >> 10;
  const int rest = blockIdx.x & 1023;
  const int qt = rest & 63;
  const int h = (rest >> 6) & 7;
  const int b = rest >> 9;
  const int bh = b * 8 + h;
  const short* Qp = Q + ((size_t)b * 1024 + qt * 16) * 512 + h * 64;
  const short* Kp = K + (size_t)b * 4096 * 512 + h * 64;
  const short* Vp = Vt + (size_t)bh * 64 * 4096;  // [64][4096]

  bf16x8 qf0 = *(const bf16x8*)(Qp + (size_t)q * 512 + g * 8);
  bf16x8 qf1 = *(const bf16x8*)(Qp + (size_t)q * 512 + 32 + g * 8);

  f32x4 acc[4] = {{0,0,0,0},{0,0,0,0},{0,0,0,0},{0,0,0,0}};
  float mrun = -1e30f, lsum = 0.0f;

  const int k0 = ks * 1024, k1 = k0 + 1024;
  for (int kb = k0; kb < k1; kb += 32) {
    const short* kp0 = Kp + (size_t)(kb + q) * 512 + g * 8;
    const short* kp1 = kp0 + (size_t)16 * 512;
    bf16x8 k00 = *(const bf16x8*)kp0;
    bf16x8 k01 = *(const bf16x8*)(kp0 + 32);
    bf16x8 k10 = *(const bf16x8*)kp1;
    bf16x8 k11 = *(const bf16x8*)(kp1 + 32);
    f32x4 s0 = {0,0,0,0}, s1 = {0,0,0,0};
    s0 = __builtin_amdgcn_mfma_f32_16x16x32_bf16(k00, qf0, s0, 0, 0, 0);
    s0 = __builtin_amdgcn_mfma_f32_16x16x32_bf16(k01, qf1, s0, 0, 0, 0);
    s1 = __builtin_amdgcn_mfma_f32_16x16x32_bf16(k10, qf0, s1, 0, 0, 0);
    s1 = __builtin_amdgcn_mfma_f32_16x16x32_bf16(k11, qf1, s1, 0, 0, 0);

    // S^T: sv[f*4+r] = score(q, key = kb + 16f + 4g + r)
    float sv[8];
    float tmax = -1e30f;
#pragma unroll
    for (int r = 0; r < 4; r++) { sv[r] = s0[r] * 0.125f; tmax = fmaxf(tmax, sv[r]); }
#pragma unroll
    for (int r = 0; r < 4; r++) { sv[4 + r] = s1[r] * 0.125f; tmax = fmaxf(tmax, sv[4 + r]); }
    tmax = fmaxf(tmax, __shfl_xor(tmax, 16));
    tmax = fmaxf(tmax, __shfl_xor(tmax, 32));

    // defer-max (T13): only rescale when tile max grew past threshold
    if (__any(tmax > mrun + 6.0f)) {
      float mnew = fmaxf(mrun, tmax);
      float corr = __expf(mrun - mnew);
      lsum *= corr;
#pragma unroll
      for (int df = 0; df < 4; df++)
#pragma unroll
        for (int r = 0; r < 4; r++) acc[df][r] *= corr;
      mrun = mnew;
    }
    float p[8], psum = 0.0f;
#pragma unroll
    for (int i = 0; i < 8; i++) { p[i] = __expf(sv[i] - mrun); psum += p[i]; }
    psum += __shfl_xor(psum, 16);
    psum += __shfl_xor(psum, 32);
    lsum += psum;

    // pack P quads; exchange -> B-frag words for keys {8g..8g+7}, col q
    unsigned w00 = pack2(p[0], p[1]), w01 = pack2(p[2], p[3]);
    unsigned w10 = pack2(p[4], p[5]), w11 = pack2(p[6], p[7]);
    int src0 = (g & 1) * 32 + q;
    int src1 = src0 + 16;
    unsigned a0 = (unsigned)__shfl((int)w00, src0);
    unsigned a1 = (unsigned)__shfl((int)w01, src0);
    unsigned c0 = (unsigned)__shfl((int)w10, src0);
    unsigned c1 = (unsigned)__shfl((int)w11, src0);
    unsigned d0 = (unsigned)__shfl((int)w00, src1);
    unsigned d1 = (unsigned)__shfl((int)w01, src1);
    unsigned e0 = (unsigned)__shfl((int)w10, src1);
    unsigned e1 = (unsigned)__shfl((int)w11, src1);
    int fsel = g >> 1;
    u32x4 pw;
    pw[0] = fsel ? c0 : a0;
    pw[1] = fsel ? c1 : a1;
    pw[2] = fsel ? e0 : d0;
    pw[3] = fsel ? e1 : d1;
    bf16x8 pfrag = __builtin_bit_cast(bf16x8, pw);

    // PV: A-frag = Vt[df*16+q][kb+g*8 .. +7] — one 16B load per df
    const short* vb = Vp + kb + g * 8;
#pragma unroll
    for (int df = 0; df < 4; df++) {
      bf16x8 vf = *(const bf16x8*)(vb + (size_t)(df * 16 + q) * 4096);
      acc[df] = __builtin_amdgcn_mfma_f32_16x16x32_bf16(vf, pfrag, acc[df], 0, 0, 0);
    }
  }

  const int row = bh * 1024 + qt * 16 + q;
  float* Op = Opart + ((size_t)ks * 16384 + row) * 64 + g * 4;
#pragma unroll
  for (int df = 0; df < 4; df++) *(f32x4*)(Op + df * 16) = acc[df];
  if (g == 0) ml[(size_t)ks * 16384 + row] = make_float2(mrun, lsum);
}

// ---------------------------------------------------------------------------
// Combine 4 k-split partials -> normalized bf16 attention output (row-major)
__global__ __launch_bounds__(256)
void attn_combine_kernel(const float* __restrict__ Opart, const float2* __restrict__ ml,
                         short* __restrict__ attnb) {
  const int qt = blockIdx.x;            // 64
  const int bh = blockIdx.y;            // 16
  const int q = threadIdx.x >> 4, dq = threadIdx.x & 15;
  const int row = bh * 1024 + qt * 16 + q;
  float2 m0 = ml[row];
  float2 m1 = ml[16384 + row];
  float2 m2 = ml[2 * 16384 + row];
  float2 m3 = ml[3 * 16384 + row];
  float M = fmaxf(fmaxf(m0.x, m1.x), fmaxf(m2.x, m3.x));
  float e0 = __expf(m0.x - M), e1 = __expf(m1.x - M);
  float e2 = __expf(m2.x - M), e3 = __expf(m3.x - M);
  float inv = 1.0f / (m0.y * e0 + m1.y * e1 + m2.y * e2 + m3.y * e3);
  const size_t base = (size_t)row * 64 + dq * 4;
  f32x4 a0 = *(const f32x4*)(Opart + base);
  f32x4 a1 = *(const f32x4*)(Opart + (size_t)16384 * 64 + base);
  f32x4 a2 = *(const f32x4*)(Opart + (size_t)2 * 16384 * 64 + base);
  f32x4 a3 = *(const f32x4*)(Opart + (size_t)3 * 16384 * 64 + base);
  bf16x4 o;
#pragma unroll
  for (int j = 0; j < 4; j++)
    o[j] = f2bf((a0[j] * e0 + a1[j] * e1 + a2[j] * e2 + a3[j] * e3) * inv);
  const int b = bh >> 3, h = bh & 7;
  *(bf16x4*)(attnb + ((size_t)b * 1024 + qt * 16 + q) * 512 + h * 64 + dq * 4) = o;
}

// ---------------------------------------------------------------------------
extern "C" void kernel_launch(void* const* d_in, const int* in_sizes, int n_in,
                              void* d_out, int out_size, void* d_ws, size_t ws_size,
                              hipStream_t stream) {
  const int D = 512, F = 2048;
  const int Mq = 2048, Mkv = 8192;

  char* ws = (char*)d_ws;
  size_t off = 0;
  auto alloc = [&](size_t bytes) { char* p = ws + off; off += (bytes + 255) & ~(size_t)255; return p; };
  float* x    = (float*)alloc((size_t)Mq * D * 4);
  short* qln  = (short*)alloc((size_t)Mq * D * 2);
  short* kvK  = (short*)alloc((size_t)Mkv * D * 2);
  short* kvV  = (short*)alloc((size_t)Mkv * D * 2);
  short* Qb   = (short*)alloc((size_t)Mq * D * 2);
  short* Kb   = (short*)alloc((size_t)Mkv * D * 2);
  short* Vt   = (short*)alloc((size_t)Mkv * D * 2);       // [16][64][4096] bf16
  short* attnb= (short*)alloc((size_t)Mq * D * 2);
  char*  big  = alloc((size_t)4 * 16384 * 64 * 4);        // Opart (16MB) / hffn (8MB) alias
  float* Opart = (float*)big;
  short* hffn  = (short*)big;
  float2* mlb = (float2*)alloc((size_t)4 * 16384 * 8);
  short* WT[8];
  for (int i = 0; i < 8; i++) WT[i] = (short*)alloc((size_t)D * D * 2);
  short* w1T = (short*)alloc((size_t)D * F * 2);
  short* w2T = (short*)alloc((size_t)F * D * 2);

  // --- all weights -> bf16 transposed, one launch ---
  TcArgs tc;
  const int widx[10] = {6, 7, 8, 9, 16, 17, 18, 19, 26, 28};
  for (int i = 0; i < 8; i++) { tc.src[i] = (const float*)d_in[widx[i]]; tc.dst[i] = WT[i]; tc.lk[i] = 9; tc.ln[i] = 9; }
  tc.src[8] = (const float*)d_in[26]; tc.dst[8] = w1T; tc.lk[8] = 9;  tc.ln[8] = 11;  // W1: K=512,N=2048
  tc.src[9] = (const float*)d_in[28]; tc.dst[9] = w2T; tc.lk[9] = 11; tc.ln[9] = 9;   // W2: K=2048,N=512
  tcast_all_kernel<<<dim3(4096, 10), 256, 0, stream>>>(tc);

  float* out = (float*)d_out;
  hipMemcpyAsync(x, d_in[0], (size_t)Mq * D * 4, hipMemcpyDeviceToDevice, stream);
  hipMemcpyAsync(out + (size_t)Mq * D, d_in[2], (size_t)Mkv * D * 4, hipMemcpyDeviceToDevice, stream);
  hipMemcpyAsync(out + (size_t)Mq * D + (size_t)Mkv * D, d_in[4], (size_t)Mkv * D * 4,
                 hipMemcpyDeviceToDevice, stream);

  auto attn_sublayer = [&](int g_i, int b_i, int kv_i, int pe_i, int w0, int bq_i, int bk_i,
                           int bv_i, int bo_i) {
    ln_kernel<1><<<Mq / 4, 256, 0, stream>>>(x, (const float*)d_in[g_i], (const float*)d_in[b_i],
                                             (const float*)d_in[1], qln);
    addpe_kernel<<<(Mkv * D) / 1024, 256, 0, stream>>>((const float*)d_in[kv_i],
                                                       (const float*)d_in[pe_i], kvK, kvV);
    gemm_kernel<0, 0, 512><<<dim3(Mq / 64, D / 64), 256, 0, stream>>>(
        qln, WT[w0], (const float*)d_in[bq_i], nullptr, Qb, Mq, D);
    gemm_kernel<0, 0, 512><<<dim3(Mkv / 64, D / 64), 256, 0, stream>>>(
        kvK, WT[w0 + 1], (const float*)d_in[bk_i], nullptr, Kb, Mkv, D);
    gemm_kernel<2, 0, 512><<<dim3(Mkv / 64, D / 64), 256, 0, stream>>>(
        kvV, WT[w0 + 2], (const float*)d_in[bv_i], nullptr, Vt, Mkv, D);
    attn_kernel<<<4096, 64, 0, stream>>>(Qb, Kb, Vt, Opart, mlb);
    attn_combine_kernel<<<dim3(64, 16), 256, 0, stream>>>(Opart, mlb, attnb);
    gemm_kernel<1, 0, 512><<<dim3(Mq / 64, D / 64), 256, 0, stream>>>(
        attnb, WT[w0 + 3], (const float*)d_in[bo_i], x, x, Mq, D);
  };

  // frame sublayer: gamma=14, beta=15, kv=2, pe=3, W=WT[0..3], biases 10..13
  attn_sublayer(14, 15, 2, 3, 0, 10, 11, 12, 13);
  // obj sublayer: gamma=24, beta=25, kv=4, pe=5, W=WT[4..7], biases 20..23
  attn_sublayer(24, 25, 4, 5, 4, 20, 21, 22, 23);

  // FFN
  ln_kernel<0><<<Mq / 4, 256, 0, stream>>>(x, (const float*)d_in[30], (const float*)d_in[31],
                                           nullptr, qln);
  gemm_kernel<0, 1, 512><<<dim3(Mq / 64, F / 64), 256, 0, stream>>>(
      qln, w1T, (const float*)d_in[27], nullptr, hffn, Mq, F);
  gemm_kernel<1, 0, 2048><<<dim3(Mq / 64, D / 64), 256, 0, stream>>>(
      hffn, w2T, (const float*)d_in[29], x, out, Mq, D);
}

// Round 3
// 545.518 us; speedup vs baseline: 1.3216x; 1.3025x over previous
//
#include <hip/hip_runtime.h>

typedef __attribute__((ext_vector_type(8))) short bf16x8;
typedef __attribute__((ext_vector_type(4))) short bf16x4;
typedef __attribute__((ext_vector_type(4))) float f32x4;
typedef __attribute__((ext_vector_type(4))) unsigned int u32x4;

#define DEV static __device__ __forceinline__

DEV short f2bf(float f) {
  union { float f; unsigned u; } v; v.f = f;
  unsigned r = v.u + 0x7fffu + ((v.u >> 16) & 1u);
  return (short)(r >> 16);
}
DEV unsigned pack2(float lo, float hi) {
  return ((unsigned)(unsigned short)f2bf(hi) << 16) | (unsigned)(unsigned short)f2bf(lo);
}

DEV void gload16(const void* g, void* l) {
  __builtin_amdgcn_global_load_lds(
      (const __attribute__((address_space(1))) unsigned int*)g,
      (__attribute__((address_space(3))) unsigned int*)l, 16, 0, 0);
}

// ---------------------------------------------------------------------------
// Coalesced weight cast+transpose via 64x64 LDS tile: Wt[n*K+k] = bf16(W[k*N+n])
DEV void ttile(const float* __restrict__ W, short* __restrict__ Wt, int K, int N,
               int k0, int n0, float (*t)[65], int tid) {
  const int c = tid & 63, r4 = tid >> 6;
#pragma unroll
  for (int i = 0; i < 16; i++)
    t[i * 4 + r4][c] = W[(size_t)(k0 + i * 4 + r4) * N + n0 + c];
  __syncthreads();
#pragma unroll
  for (int i = 0; i < 16; i++)
    Wt[(size_t)(n0 + i * 4 + r4) * K + k0 + c] = f2bf(t[c][i * 4 + r4]);
}

struct Tc8 { const float* src[8]; short* dst[8]; };

__global__ __launch_bounds__(256)
void tcast_tile8_kernel(Tc8 a) {  // 8 DxD weights, grid (8,8,8)
  __shared__ float t[64][65];
  ttile(a.src[blockIdx.z], a.dst[blockIdx.z], 512, 512,
        blockIdx.x * 64, blockIdx.y * 64, t, threadIdx.x);
}

__global__ __launch_bounds__(256)
void tcast_tile_kernel(const float* __restrict__ W, short* __restrict__ Wt, int K, int N) {
  __shared__ float t[64][65];
  ttile(W, Wt, K, N, blockIdx.x * 64, blockIdx.y * 64, t, threadIdx.x);
}

// ---------------------------------------------------------------------------
// kvK = bf16(a+pe), kvV = bf16(a); 4 elems/thread
__global__ __launch_bounds__(256)
void addpe_kernel(const float* __restrict__ a, const float* __restrict__ p,
                  short* __restrict__ outK, short* __restrict__ outV) {
  size_t i = (size_t)(blockIdx.x * 256 + threadIdx.x) * 4;
  f32x4 va = *(const f32x4*)(a + i);
  f32x4 vp = *(const f32x4*)(p + i);
  bf16x4 k, v;
#pragma unroll
  for (int j = 0; j < 4; j++) { k[j] = f2bf(va[j] + vp[j]); v[j] = f2bf(va[j]); }
  *(bf16x4*)(outK + i) = k;
  *(bf16x4*)(outV + i) = v;
}

// ---------------------------------------------------------------------------
// LayerNorm over D=512, one wave per row, optional +pe, bf16 out
template<int PE>
__global__ __launch_bounds__(256)
void ln_kernel(const float* __restrict__ X, const float* __restrict__ gamma,
               const float* __restrict__ beta, const float* __restrict__ pe,
               short* __restrict__ Y) {
  const int wave = threadIdx.x >> 6, lane = threadIdx.x & 63;
  const int row = blockIdx.x * 4 + wave;
  const float* x = X + (size_t)row * 512 + lane * 8;
  f32x4 v0 = *(const f32x4*)x;
  f32x4 v1 = *(const f32x4*)(x + 4);
  float s = ((v0[0] + v0[1]) + (v0[2] + v0[3])) + ((v1[0] + v1[1]) + (v1[2] + v1[3]));
#pragma unroll
  for (int m = 1; m < 64; m <<= 1) s += __shfl_xor(s, m);
  float mu = s * (1.0f / 512.0f);
  float vs = 0.0f;
#pragma unroll
  for (int j = 0; j < 4; j++) { float d = v0[j] - mu; vs += d * d; }
#pragma unroll
  for (int j = 0; j < 4; j++) { float d = v1[j] - mu; vs += d * d; }
#pragma unroll
  for (int m = 1; m < 64; m <<= 1) vs += __shfl_xor(vs, m);
  float rstd = rsqrtf(vs * (1.0f / 512.0f) + 1e-6f);
  const int c = lane * 8;
  f32x4 g0 = *(const f32x4*)(gamma + c);
  f32x4 g1 = *(const f32x4*)(gamma + c + 4);
  f32x4 b0 = *(const f32x4*)(beta + c);
  f32x4 b1 = *(const f32x4*)(beta + c + 4);
  f32x4 p0 = {0,0,0,0}, p1 = {0,0,0,0};
  if (PE) {
    p0 = *(const f32x4*)(pe + (size_t)row * 512 + c);
    p1 = *(const f32x4*)(pe + (size_t)row * 512 + c + 4);
  }
  bf16x8 out;
#pragma unroll
  for (int j = 0; j < 4; j++) out[j]     = f2bf((v0[j] - mu) * rstd * g0[j] + b0[j] + p0[j]);
#pragma unroll
  for (int j = 0; j < 4; j++) out[4 + j] = f2bf((v1[j] - mu) * rstd * g1[j] + b1[j] + p1[j]);
  *(bf16x8*)(Y + (size_t)row * 512 + c) = out;
}

// ---------------------------------------------------------------------------
// GEMM: C(M,N) = act(A(M,K)bf16 @ Wt(N,K)^T bf16 + bias)
// OUTMODE: 0 = bf16 row-major, 1 = f32 row-major + residual, 2 = bf16 V-transposed
template<int OUTMODE, int RELU, int K>
__global__ __launch_bounds__(256)
void gemm_kernel(const short* __restrict__ A, const short* __restrict__ Bt,
                 const float* __restrict__ bias, const float* __restrict__ res,
                 void* __restrict__ Cv, int M, int N) {
  const int lane = threadIdx.x & 63;
  const int wave = threadIdx.x >> 6;
  const int g = lane >> 4, x15 = lane & 15;
  const int wm = wave >> 1, wn = wave & 1;
  const int Mb = blockIdx.x * 64, Nb = blockIdx.y * 64;

  f32x4 acc[2][2] = {{{0,0,0,0},{0,0,0,0}},{{0,0,0,0},{0,0,0,0}}};
  const short* Arow = A + (size_t)(Mb + wm * 32 + x15) * K + g * 8;
  const short* Brow = Bt + (size_t)(Nb + wn * 32 + x15) * K + g * 8;
#pragma unroll 4
  for (int kk = 0; kk < K; kk += 32) {
    bf16x8 a0 = *(const bf16x8*)(Arow + kk);
    bf16x8 a1 = *(const bf16x8*)(Arow + (size_t)16 * K + kk);
    bf16x8 b0 = *(const bf16x8*)(Brow + kk);
    bf16x8 b1 = *(const bf16x8*)(Brow + (size_t)16 * K + kk);
    acc[0][0] = __builtin_amdgcn_mfma_f32_16x16x32_bf16(a0, b0, acc[0][0], 0, 0, 0);
    acc[0][1] = __builtin_amdgcn_mfma_f32_16x16x32_bf16(a0, b1, acc[0][1], 0, 0, 0);
    acc[1][0] = __builtin_amdgcn_mfma_f32_16x16x32_bf16(a1, b0, acc[1][0], 0, 0, 0);
    acc[1][1] = __builtin_amdgcn_mfma_f32_16x16x32_bf16(a1, b1, acc[1][1], 0, 0, 0);
  }
#pragma unroll
  for (int fm = 0; fm < 2; fm++)
#pragma unroll
    for (int fn = 0; fn < 2; fn++) {
      int n = Nb + wn * 32 + fn * 16 + x15;
      float bs = bias[n];
      int m0 = Mb + wm * 32 + fm * 16 + g * 4;
      if (OUTMODE == 2) {
        int bh = ((m0 >> 12) << 3) + (n >> 6);
        bf16x4 ov;
#pragma unroll
        for (int r = 0; r < 4; r++) ov[r] = f2bf(acc[fm][fn][r] + bs);
        *(bf16x4*)((short*)Cv + ((size_t)bh * 64 + (n & 63)) * 4096 + (m0 & 4095)) = ov;
      } else {
#pragma unroll
        for (int r = 0; r < 4; r++) {
          int m = m0 + r;
          float v = acc[fm][fn][r] + bs;
          if (RELU) v = fmaxf(v, 0.0f);
          if (OUTMODE == 1) {
            ((float*)Cv)[(size_t)m * N + n] = res[(size_t)m * N + n] + v;
          } else {
            ((short*)Cv)[(size_t)m * N + n] = f2bf(v);
          }
        }
      }
    }
}

// ---------------------------------------------------------------------------
// Flash attention v3: k-split x4, 4-wave blocks sharing LDS K/V tiles.
// Block = (ks, bh, qtg): 4 waves, wave w handles q-tile qtg*4+w (16 q-rows).
// KVBLK=64 staged per iteration via global_load_lds with pre-swizzled source;
// frag reads XOR-swizzled ds_read_b128 (byte ^= (row&7)<<4). Double-buffered.
__global__ __launch_bounds__(256, 4)
void attn_kernel(const short* __restrict__ Q, const short* __restrict__ K,
                 const short* __restrict__ Vt, float* __restrict__ Opart,
                 float2* __restrict__ ml) {
  __shared__ short Kl[2][4096];  // [key 64][d 64] swizzled, 8KB each buf
  __shared__ short Vl[2][4096];  // [d 64][key 64] swizzled

  const int tid = threadIdx.x;
  const int lane = tid & 63, w = tid >> 6;
  const int g = lane >> 4, q = lane & 15;
  // XCD-bijective swizzle: 1024 blocks, 8 XCDs, 128 chunked per XCD
  const int o = (blockIdx.x & 7) * 128 + (blockIdx.x >> 3);
  const int ks = o >> 8, bh = (o >> 4) & 15, qtg = o & 15;
  const int b = bh >> 3, h = bh & 7;
  const int qt = qtg * 4 + w;

  const char* Kg = (const char*)K + ((size_t)b * 4096 * 512 + h * 64) * 2;
  const char* Vg = (const char*)Vt + ((size_t)bh * 64 * 4096) * 2;
  const int swz = (((lane & 7) ^ (lane >> 3)) << 4);  // src pre-swizzle, rows 8t+(l>>3)
  const int sw = (q & 7) << 4;                        // read-side swizzle

  const short* Qp = Q + ((size_t)b * 1024 + qt * 16) * 512 + h * 64;
  bf16x8 qf0 = *(const bf16x8*)(Qp + (size_t)q * 512 + g * 8);
  bf16x8 qf1 = *(const bf16x8*)(Qp + (size_t)q * 512 + 32 + g * 8);

  f32x4 acc[4] = {{0,0,0,0},{0,0,0,0},{0,0,0,0},{0,0,0,0}};
  float mrun = -1e30f, lsum = 0.0f;
  const int k0 = ks * 1024;
  const int r0 = w * 16;  // this wave's 16-row staging quarter

  auto stage = [&](int kb, int cur) {
    const char* kg = Kg + (size_t)(kb + r0 + (lane >> 3)) * 1024 + swz;
    gload16(kg,            &Kl[cur][r0 * 64]);
    gload16(kg + 8 * 1024, &Kl[cur][(r0 + 8) * 64]);
    const char* vg = Vg + (size_t)(r0 + (lane >> 3)) * 8192 + (size_t)kb * 2 + swz;
    gload16(vg,            &Vl[cur][r0 * 64]);
    gload16(vg + 8 * 8192, &Vl[cur][(r0 + 8) * 64]);
  };

  stage(k0, 0);
  __syncthreads();
  int cur = 0;
  for (int t = 0; t < 16; t++) {
    if (t < 15) stage(k0 + (t + 1) * 64, cur ^ 1);
    const char* Kc = (const char*)&Kl[cur][0];
    const char* Vc = (const char*)&Vl[cur][0];
#pragma unroll
    for (int ks32 = 0; ks32 < 2; ks32++) {
      const char* Kb8 = Kc + ks32 * 4096;
      bf16x8 k00 = *(const bf16x8*)(Kb8 + q * 128        + ((g * 16) ^ sw));
      bf16x8 k01 = *(const bf16x8*)(Kb8 + q * 128        + ((64 + g * 16) ^ sw));
      bf16x8 k10 = *(const bf16x8*)(Kb8 + (q + 16) * 128 + ((g * 16) ^ sw));
      bf16x8 k11 = *(const bf16x8*)(Kb8 + (q + 16) * 128 + ((64 + g * 16) ^ sw));
      f32x4 s0 = {0,0,0,0}, s1 = {0,0,0,0};
      s0 = __builtin_amdgcn_mfma_f32_16x16x32_bf16(k00, qf0, s0, 0, 0, 0);
      s0 = __builtin_amdgcn_mfma_f32_16x16x32_bf16(k01, qf1, s0, 0, 0, 0);
      s1 = __builtin_amdgcn_mfma_f32_16x16x32_bf16(k10, qf0, s1, 0, 0, 0);
      s1 = __builtin_amdgcn_mfma_f32_16x16x32_bf16(k11, qf1, s1, 0, 0, 0);

      float sv[8];
      float tmax = -1e30f;
#pragma unroll
      for (int r = 0; r < 4; r++) { sv[r] = s0[r] * 0.125f; tmax = fmaxf(tmax, sv[r]); }
#pragma unroll
      for (int r = 0; r < 4; r++) { sv[4 + r] = s1[r] * 0.125f; tmax = fmaxf(tmax, sv[4 + r]); }
      tmax = fmaxf(tmax, __shfl_xor(tmax, 16));
      tmax = fmaxf(tmax, __shfl_xor(tmax, 32));

      if (__any(tmax > mrun + 6.0f)) {
        float mnew = fmaxf(mrun, tmax);
        float corr = __expf(mrun - mnew);
        lsum *= corr;
#pragma unroll
        for (int df = 0; df < 4; df++)
#pragma unroll
          for (int r = 0; r < 4; r++) acc[df][r] *= corr;
        mrun = mnew;
      }
      float p[8], psum = 0.0f;
#pragma unroll
      for (int i = 0; i < 8; i++) { p[i] = __expf(sv[i] - mrun); psum += p[i]; }
      psum += __shfl_xor(psum, 16);
      psum += __shfl_xor(psum, 32);
      lsum += psum;

      unsigned w00 = pack2(p[0], p[1]), w01 = pack2(p[2], p[3]);
      unsigned w10 = pack2(p[4], p[5]), w11 = pack2(p[6], p[7]);
      int src0 = (g & 1) * 32 + q;
      int src1 = src0 + 16;
      unsigned a0 = (unsigned)__shfl((int)w00, src0);
      unsigned a1 = (unsigned)__shfl((int)w01, src0);
      unsigned c0 = (unsigned)__shfl((int)w10, src0);
      unsigned c1 = (unsigned)__shfl((int)w11, src0);
      unsigned d0 = (unsigned)__shfl((int)w00, src1);
      unsigned d1 = (unsigned)__shfl((int)w01, src1);
      unsigned e0 = (unsigned)__shfl((int)w10, src1);
      unsigned e1 = (unsigned)__shfl((int)w11, src1);
      int fsel = g >> 1;
      u32x4 pw;
      pw[0] = fsel ? c0 : a0;
      pw[1] = fsel ? c1 : a1;
      pw[2] = fsel ? e0 : d0;
      pw[3] = fsel ? e1 : d1;
      bf16x8 pfrag = __builtin_bit_cast(bf16x8, pw);

#pragma unroll
      for (int df = 0; df < 4; df++) {
        bf16x8 vf = *(const bf16x8*)(Vc + (df * 16 + q) * 128 + ((ks32 * 64 + g * 16) ^ sw));
        acc[df] = __builtin_amdgcn_mfma_f32_16x16x32_bf16(vf, pfrag, acc[df], 0, 0, 0);
      }
    }
    __syncthreads();
    cur ^= 1;
  }

  const int row = bh * 1024 + qt * 16 + q;
  float* Op = Opart + ((size_t)ks * 16384 + row) * 64 + g * 4;
#pragma unroll
  for (int df = 0; df < 4; df++) *(f32x4*)(Op + df * 16) = acc[df];
  if (g == 0) ml[(size_t)ks * 16384 + row] = make_float2(mrun, lsum);
}

// ---------------------------------------------------------------------------
// Combine 4 k-split partials -> normalized bf16 attention output (row-major)
__global__ __launch_bounds__(256)
void attn_combine_kernel(const float* __restrict__ Opart, const float2* __restrict__ ml,
                         short* __restrict__ attnb) {
  const int qt = blockIdx.x;
  const int bh = blockIdx.y;
  const int q = threadIdx.x >> 4, dq = threadIdx.x & 15;
  const int row = bh * 1024 + qt * 16 + q;
  float2 m0 = ml[row];
  float2 m1 = ml[16384 + row];
  float2 m2 = ml[2 * 16384 + row];
  float2 m3 = ml[3 * 16384 + row];
  float M = fmaxf(fmaxf(m0.x, m1.x), fmaxf(m2.x, m3.x));
  float e0 = __expf(m0.x - M), e1 = __expf(m1.x - M);
  float e2 = __expf(m2.x - M), e3 = __expf(m3.x - M);
  float inv = 1.0f / (m0.y * e0 + m1.y * e1 + m2.y * e2 + m3.y * e3);
  const size_t base = (size_t)row * 64 + dq * 4;
  f32x4 a0 = *(const f32x4*)(Opart + base);
  f32x4 a1 = *(const f32x4*)(Opart + (size_t)16384 * 64 + base);
  f32x4 a2 = *(const f32x4*)(Opart + (size_t)2 * 16384 * 64 + base);
  f32x4 a3 = *(const f32x4*)(Opart + (size_t)3 * 16384 * 64 + base);
  bf16x4 oo;
#pragma unroll
  for (int j = 0; j < 4; j++)
    oo[j] = f2bf((a0[j] * e0 + a1[j] * e1 + a2[j] * e2 + a3[j] * e3) * inv);
  const int b = bh >> 3, h = bh & 7;
  *(bf16x4*)(attnb + ((size_t)b * 1024 + qt * 16 + q) * 512 + h * 64 + dq * 4) = oo;
}

// ---------------------------------------------------------------------------
extern "C" void kernel_launch(void* const* d_in, const int* in_sizes, int n_in,
                              void* d_out, int out_size, void* d_ws, size_t ws_size,
                              hipStream_t stream) {
  const int D = 512, F = 2048;
  const int Mq = 2048, Mkv = 8192;

  char* ws = (char*)d_ws;
  size_t off = 0;
  auto alloc = [&](size_t bytes) { char* p = ws + off; off += (bytes + 255) & ~(size_t)255; return p; };
  float* x    = (float*)alloc((size_t)Mq * D * 4);
  short* qln  = (short*)alloc((size_t)Mq * D * 2);
  short* kvK  = (short*)alloc((size_t)Mkv * D * 2);
  short* kvV  = (short*)alloc((size_t)Mkv * D * 2);
  short* Qb   = (short*)alloc((size_t)Mq * D * 2);
  short* Kb   = (short*)alloc((size_t)Mkv * D * 2);
  short* Vt   = (short*)alloc((size_t)Mkv * D * 2);
  short* attnb= (short*)alloc((size_t)Mq * D * 2);
  char*  big  = alloc((size_t)4 * 16384 * 64 * 4);
  float* Opart = (float*)big;
  short* hffn  = (short*)big;
  float2* mlb = (float2*)alloc((size_t)4 * 16384 * 8);
  short* WT[8];
  for (int i = 0; i < 8; i++) WT[i] = (short*)alloc((size_t)D * D * 2);
  short* w1T = (short*)alloc((size_t)D * F * 2);
  short* w2T = (short*)alloc((size_t)F * D * 2);

  // --- weights -> bf16 transposed, coalesced LDS-tile transpose ---
  Tc8 tc8;
  const int widx[8] = {6, 7, 8, 9, 16, 17, 18, 19};
  for (int i = 0; i < 8; i++) { tc8.src[i] = (const float*)d_in[widx[i]]; tc8.dst[i] = WT[i]; }
  tcast_tile8_kernel<<<dim3(8, 8, 8), 256, 0, stream>>>(tc8);
  tcast_tile_kernel<<<dim3(8, 32), 256, 0, stream>>>((const float*)d_in[26], w1T, 512, 2048);
  tcast_tile_kernel<<<dim3(32, 8), 256, 0, stream>>>((const float*)d_in[28], w2T, 2048, 512);

  float* out = (float*)d_out;
  hipMemcpyAsync(x, d_in[0], (size_t)Mq * D * 4, hipMemcpyDeviceToDevice, stream);
  hipMemcpyAsync(out + (size_t)Mq * D, d_in[2], (size_t)Mkv * D * 4, hipMemcpyDeviceToDevice, stream);
  hipMemcpyAsync(out + (size_t)Mq * D + (size_t)Mkv * D, d_in[4], (size_t)Mkv * D * 4,
                 hipMemcpyDeviceToDevice, stream);

  auto attn_sublayer = [&](int g_i, int b_i, int kv_i, int pe_i, int w0, int bq_i, int bk_i,
                           int bv_i, int bo_i) {
    ln_kernel<1><<<Mq / 4, 256, 0, stream>>>(x, (const float*)d_in[g_i], (const float*)d_in[b_i],
                                             (const float*)d_in[1], qln);
    addpe_kernel<<<(Mkv * D) / 1024, 256, 0, stream>>>((const float*)d_in[kv_i],
                                                       (const float*)d_in[pe_i], kvK, kvV);
    gemm_kernel<0, 0, 512><<<dim3(Mq / 64, D / 64), 256, 0, stream>>>(
        qln, WT[w0], (const float*)d_in[bq_i], nullptr, Qb, Mq, D);
    gemm_kernel<0, 0, 512><<<dim3(Mkv / 64, D / 64), 256, 0, stream>>>(
        kvK, WT[w0 + 1], (const float*)d_in[bk_i], nullptr, Kb, Mkv, D);
    gemm_kernel<2, 0, 512><<<dim3(Mkv / 64, D / 64), 256, 0, stream>>>(
        kvV, WT[w0 + 2], (const float*)d_in[bv_i], nullptr, Vt, Mkv, D);
    attn_kernel<<<1024, 256, 0, stream>>>(Qb, Kb, Vt, Opart, mlb);
    attn_combine_kernel<<<dim3(64, 16), 256, 0, stream>>>(Opart, mlb, attnb);
    gemm_kernel<1, 0, 512><<<dim3(Mq / 64, D / 64), 256, 0, stream>>>(
        attnb, WT[w0 + 3], (const float*)d_in[bo_i], x, x, Mq, D);
  };

  attn_sublayer(14, 15, 2, 3, 0, 10, 11, 12, 13);
  attn_sublayer(24, 25, 4, 5, 4, 20, 21, 22, 23);

  // FFN
  ln_kernel<0><<<Mq / 4, 256, 0, stream>>>(x, (const float*)d_in[30], (const float*)d_in[31],
                                           nullptr, qln);
  gemm_kernel<0, 1, 512><<<dim3(Mq / 64, F / 64), 256, 0, stream>>>(
      qln, w1T, (const float*)d_in[27], nullptr, hffn, Mq, F);
  gemm_kernel<1, 0, 2048><<<dim3(Mq / 64, D / 64), 256, 0, stream>>>(
      hffn, w2T, (const float*)d_in[29], x, out, Mq, D);
}

// Round 4
// 434.398 us; speedup vs baseline: 1.6596x; 1.2558x over previous
//
#include <hip/hip_runtime.h>

typedef __attribute__((ext_vector_type(8))) short bf16x8;
typedef __attribute__((ext_vector_type(4))) short bf16x4;
typedef __attribute__((ext_vector_type(4))) float f32x4;
typedef __attribute__((ext_vector_type(4))) unsigned int u32x4;

#define DEV static __device__ __forceinline__

DEV short f2bf(float f) {
  union { float f; unsigned u; } v; v.f = f;
  unsigned r = v.u + 0x7fffu + ((v.u >> 16) & 1u);
  return (short)(r >> 16);
}
DEV unsigned pack2(float lo, float hi) {
  return ((unsigned)(unsigned short)f2bf(hi) << 16) | (unsigned)(unsigned short)f2bf(lo);
}

DEV void gload16(const void* g, void* l) {
  __builtin_amdgcn_global_load_lds(
      (const __attribute__((address_space(1))) unsigned int*)g,
      (__attribute__((address_space(3))) unsigned int*)l, 16, 0, 0);
}

// ---------------------------------------------------------------------------
// Coalesced weight cast+transpose via 64x64 LDS tile: Wt[n*K+k] = bf16(W[k*N+n])
DEV void ttile(const float* __restrict__ W, short* __restrict__ Wt, int K, int N,
               int k0, int n0, float (*t)[65], int tid) {
  const int c = tid & 63, r4 = tid >> 6;
#pragma unroll
  for (int i = 0; i < 16; i++)
    t[i * 4 + r4][c] = W[(size_t)(k0 + i * 4 + r4) * N + n0 + c];
  __syncthreads();
#pragma unroll
  for (int i = 0; i < 16; i++)
    Wt[(size_t)(n0 + i * 4 + r4) * K + k0 + c] = f2bf(t[c][i * 4 + r4]);
}

struct Tc8 { const float* src[8]; short* dst[8]; };

__global__ __launch_bounds__(256)
void tcast_tile8_kernel(Tc8 a) {
  __shared__ float t[64][65];
  ttile(a.src[blockIdx.z], a.dst[blockIdx.z], 512, 512,
        blockIdx.x * 64, blockIdx.y * 64, t, threadIdx.x);
}

__global__ __launch_bounds__(256)
void tcast_tile_kernel(const float* __restrict__ W, short* __restrict__ Wt, int K, int N) {
  __shared__ float t[64][65];
  ttile(W, Wt, K, N, blockIdx.x * 64, blockIdx.y * 64, t, threadIdx.x);
}

// ---------------------------------------------------------------------------
// kvK = bf16(a+pe), kvV = bf16(a); 4 elems/thread
__global__ __launch_bounds__(256)
void addpe_kernel(const float* __restrict__ a, const float* __restrict__ p,
                  short* __restrict__ outK, short* __restrict__ outV) {
  size_t i = (size_t)(blockIdx.x * 256 + threadIdx.x) * 4;
  f32x4 va = *(const f32x4*)(a + i);
  f32x4 vp = *(const f32x4*)(p + i);
  bf16x4 k, v;
#pragma unroll
  for (int j = 0; j < 4; j++) { k[j] = f2bf(va[j] + vp[j]); v[j] = f2bf(va[j]); }
  *(bf16x4*)(outK + i) = k;
  *(bf16x4*)(outV + i) = v;
}

// ---------------------------------------------------------------------------
// LayerNorm over D=512, one wave per row, optional +pe, bf16 out
template<int PE>
__global__ __launch_bounds__(256)
void ln_kernel(const float* __restrict__ X, const float* __restrict__ gamma,
               const float* __restrict__ beta, const float* __restrict__ pe,
               short* __restrict__ Y) {
  const int wave = threadIdx.x >> 6, lane = threadIdx.x & 63;
  const int row = blockIdx.x * 4 + wave;
  const float* x = X + (size_t)row * 512 + lane * 8;
  f32x4 v0 = *(const f32x4*)x;
  f32x4 v1 = *(const f32x4*)(x + 4);
  float s = ((v0[0] + v0[1]) + (v0[2] + v0[3])) + ((v1[0] + v1[1]) + (v1[2] + v1[3]));
#pragma unroll
  for (int m = 1; m < 64; m <<= 1) s += __shfl_xor(s, m);
  float mu = s * (1.0f / 512.0f);
  float vs = 0.0f;
#pragma unroll
  for (int j = 0; j < 4; j++) { float d = v0[j] - mu; vs += d * d; }
#pragma unroll
  for (int j = 0; j < 4; j++) { float d = v1[j] - mu; vs += d * d; }
#pragma unroll
  for (int m = 1; m < 64; m <<= 1) vs += __shfl_xor(vs, m);
  float rstd = rsqrtf(vs * (1.0f / 512.0f) + 1e-6f);
  const int c = lane * 8;
  f32x4 g0 = *(const f32x4*)(gamma + c);
  f32x4 g1 = *(const f32x4*)(gamma + c + 4);
  f32x4 b0 = *(const f32x4*)(beta + c);
  f32x4 b1 = *(const f32x4*)(beta + c + 4);
  f32x4 p0 = {0,0,0,0}, p1 = {0,0,0,0};
  if (PE) {
    p0 = *(const f32x4*)(pe + (size_t)row * 512 + c);
    p1 = *(const f32x4*)(pe + (size_t)row * 512 + c + 4);
  }
  bf16x8 out;
#pragma unroll
  for (int j = 0; j < 4; j++) out[j]     = f2bf((v0[j] - mu) * rstd * g0[j] + b0[j] + p0[j]);
#pragma unroll
  for (int j = 0; j < 4; j++) out[4 + j] = f2bf((v1[j] - mu) * rstd * g1[j] + b1[j] + p1[j]);
  *(bf16x8*)(Y + (size_t)row * 512 + c) = out;
}

// ---------------------------------------------------------------------------
// GEMM v2 (m97 structure): LDS-staged, double-buffered, XOR-swizzled.
// Tile BM=32*FM x BN=32*FN, 4 waves (2x2), wave computes FM x FN 16x16 frags.
// OUTMODE: 0 = bf16 row-major, 1 = f32 row-major + residual, 2 = bf16 V-transposed
template<int FM, int FN, int OUTMODE, int RELU>
__global__ __launch_bounds__(256)
void gemm2_kernel(const short* __restrict__ A, const short* __restrict__ Bt,
                  const float* __restrict__ bias, const float* __restrict__ res,
                  void* __restrict__ Cv, int M, int N, int Klen, int lda, int ldb) {
  constexpr int BM = 32 * FM, BN = 32 * FN;
  __shared__ alignas(16) short As[2][BM * 32];
  __shared__ alignas(16) short Bs[2][BN * 32];
  const int tid = threadIdx.x;
  const int lane = tid & 63, w = tid >> 6;
  const int g = lane >> 4, x15 = lane & 15;
  const int wm = w >> 1, wn = w & 1;
  const int Mb = blockIdx.x * BM, Nb = blockIdx.y * BN;
  const short* Ag = A + (size_t)Mb * lda;
  const short* Bg = Bt + (size_t)Nb * ldb;

  // Stage: LDS holds row-major [rows][32] with 16B slot c permuted by c^(row&3).
  // global_load_lds dest is linear (base + lane*16); source carries the swizzle.
  auto stage = [&](int kb, int cur) {
    const int c = tid & 3, rr = tid >> 2;
#pragma unroll
    for (int j = 0; j < BM / 64; j++) {
      int row = j * 64 + rr;
      gload16(Ag + (size_t)row * lda + kb + ((c ^ (row & 3)) << 3),
              &As[cur][j * 2048 + tid * 8]);
    }
#pragma unroll
    for (int j = 0; j < BN / 64; j++) {
      int row = j * 64 + rr;
      gload16(Bg + (size_t)row * ldb + kb + ((c ^ (row & 3)) << 3),
              &Bs[cur][j * 2048 + tid * 8]);
    }
  };

  f32x4 acc[FM][FN] = {};
  const int nt = Klen >> 5;
  stage(0, 0);
  __syncthreads();
  int cur = 0;
  for (int t = 0; t < nt; t++) {
    if (t + 1 < nt) stage((t + 1) << 5, cur ^ 1);
    const char* Ac = (const char*)&As[cur][0];
    const char* Bc = (const char*)&Bs[cur][0];
    const int swr = (g ^ (x15 & 3)) << 4;
    bf16x8 af[FM], bfr[FN];
#pragma unroll
    for (int fm = 0; fm < FM; fm++)
      af[fm] = *(const bf16x8*)(Ac + (wm * (BM / 2) + fm * 16 + x15) * 64 + swr);
#pragma unroll
    for (int fn = 0; fn < FN; fn++)
      bfr[fn] = *(const bf16x8*)(Bc + (wn * (BN / 2) + fn * 16 + x15) * 64 + swr);
#pragma unroll
    for (int fm = 0; fm < FM; fm++)
#pragma unroll
      for (int fn = 0; fn < FN; fn++)
        acc[fm][fn] = __builtin_amdgcn_mfma_f32_16x16x32_bf16(af[fm], bfr[fn], acc[fm][fn], 0, 0, 0);
    __syncthreads();
    cur ^= 1;
  }

#pragma unroll
  for (int fm = 0; fm < FM; fm++)
#pragma unroll
    for (int fn = 0; fn < FN; fn++) {
      int n = Nb + wn * (BN / 2) + fn * 16 + x15;
      float bs = bias[n];
      int m0 = Mb + wm * (BM / 2) + fm * 16 + g * 4;
      if (OUTMODE == 2) {
        int bh = ((m0 >> 12) << 3) + (n >> 6);
        bf16x4 ov;
#pragma unroll
        for (int r = 0; r < 4; r++) ov[r] = f2bf(acc[fm][fn][r] + bs);
        *(bf16x4*)((short*)Cv + ((size_t)bh * 64 + (n & 63)) * 4096 + (m0 & 4095)) = ov;
      } else {
#pragma unroll
        for (int r = 0; r < 4; r++) {
          int m = m0 + r;
          float v = acc[fm][fn][r] + bs;
          if (RELU) v = fmaxf(v, 0.0f);
          if (OUTMODE == 1) {
            ((float*)Cv)[(size_t)m * N + n] = res[(size_t)m * N + n] + v;
          } else {
            ((short*)Cv)[(size_t)m * N + n] = f2bf(v);
          }
        }
      }
    }
}

// ---------------------------------------------------------------------------
// Flash attention v3: k-split x4, 4-wave blocks sharing LDS K/V tiles.
__global__ __launch_bounds__(256, 4)
void attn_kernel(const short* __restrict__ Q, const short* __restrict__ K,
                 const short* __restrict__ Vt, float* __restrict__ Opart,
                 float2* __restrict__ ml) {
  __shared__ alignas(16) short Kl[2][4096];
  __shared__ alignas(16) short Vl[2][4096];

  const int tid = threadIdx.x;
  const int lane = tid & 63, w = tid >> 6;
  const int g = lane >> 4, q = lane & 15;
  const int o = (blockIdx.x & 7) * 128 + (blockIdx.x >> 3);
  const int ks = o >> 8, bh = (o >> 4) & 15, qtg = o & 15;
  const int b = bh >> 3, h = bh & 7;
  const int qt = qtg * 4 + w;

  const char* Kg = (const char*)K + ((size_t)b * 4096 * 512 + h * 64) * 2;
  const char* Vg = (const char*)Vt + ((size_t)bh * 64 * 4096) * 2;
  const int swz = (((lane & 7) ^ (lane >> 3)) << 4);
  const int sw = (q & 7) << 4;

  const short* Qp = Q + ((size_t)b * 1024 + qt * 16) * 512 + h * 64;
  bf16x8 qf0 = *(const bf16x8*)(Qp + (size_t)q * 512 + g * 8);
  bf16x8 qf1 = *(const bf16x8*)(Qp + (size_t)q * 512 + 32 + g * 8);

  f32x4 acc[4] = {{0,0,0,0},{0,0,0,0},{0,0,0,0},{0,0,0,0}};
  float mrun = -1e30f, lsum = 0.0f;
  const int k0 = ks * 1024;
  const int r0 = w * 16;

  auto stage = [&](int kb, int cur) {
    const char* kg = Kg + (size_t)(kb + r0 + (lane >> 3)) * 1024 + swz;
    gload16(kg,            &Kl[cur][r0 * 64]);
    gload16(kg + 8 * 1024, &Kl[cur][(r0 + 8) * 64]);
    const char* vg = Vg + (size_t)(r0 + (lane >> 3)) * 8192 + (size_t)kb * 2 + swz;
    gload16(vg,            &Vl[cur][r0 * 64]);
    gload16(vg + 8 * 8192, &Vl[cur][(r0 + 8) * 64]);
  };

  stage(k0, 0);
  __syncthreads();
  int cur = 0;
  for (int t = 0; t < 16; t++) {
    if (t < 15) stage(k0 + (t + 1) * 64, cur ^ 1);
    const char* Kc = (const char*)&Kl[cur][0];
    const char* Vc = (const char*)&Vl[cur][0];
#pragma unroll
    for (int ks32 = 0; ks32 < 2; ks32++) {
      const char* Kb8 = Kc + ks32 * 4096;
      bf16x8 k00 = *(const bf16x8*)(Kb8 + q * 128        + ((g * 16) ^ sw));
      bf16x8 k01 = *(const bf16x8*)(Kb8 + q * 128        + ((64 + g * 16) ^ sw));
      bf16x8 k10 = *(const bf16x8*)(Kb8 + (q + 16) * 128 + ((g * 16) ^ sw));
      bf16x8 k11 = *(const bf16x8*)(Kb8 + (q + 16) * 128 + ((64 + g * 16) ^ sw));
      f32x4 s0 = {0,0,0,0}, s1 = {0,0,0,0};
      __builtin_amdgcn_s_setprio(1);
      s0 = __builtin_amdgcn_mfma_f32_16x16x32_bf16(k00, qf0, s0, 0, 0, 0);
      s0 = __builtin_amdgcn_mfma_f32_16x16x32_bf16(k01, qf1, s0, 0, 0, 0);
      s1 = __builtin_amdgcn_mfma_f32_16x16x32_bf16(k10, qf0, s1, 0, 0, 0);
      s1 = __builtin_amdgcn_mfma_f32_16x16x32_bf16(k11, qf1, s1, 0, 0, 0);
      __builtin_amdgcn_s_setprio(0);

      float sv[8];
      float tmax = -1e30f;
#pragma unroll
      for (int r = 0; r < 4; r++) { sv[r] = s0[r] * 0.125f; tmax = fmaxf(tmax, sv[r]); }
#pragma unroll
      for (int r = 0; r < 4; r++) { sv[4 + r] = s1[r] * 0.125f; tmax = fmaxf(tmax, sv[4 + r]); }
      tmax = fmaxf(tmax, __shfl_xor(tmax, 16));
      tmax = fmaxf(tmax, __shfl_xor(tmax, 32));

      if (__any(tmax > mrun + 6.0f)) {
        float mnew = fmaxf(mrun, tmax);
        float corr = __expf(mrun - mnew);
        lsum *= corr;
#pragma unroll
        for (int df = 0; df < 4; df++)
#pragma unroll
          for (int r = 0; r < 4; r++) acc[df][r] *= corr;
        mrun = mnew;
      }
      float p[8], psum = 0.0f;
#pragma unroll
      for (int i = 0; i < 8; i++) { p[i] = __expf(sv[i] - mrun); psum += p[i]; }
      psum += __shfl_xor(psum, 16);
      psum += __shfl_xor(psum, 32);
      lsum += psum;

      unsigned w00 = pack2(p[0], p[1]), w01 = pack2(p[2], p[3]);
      unsigned w10 = pack2(p[4], p[5]), w11 = pack2(p[6], p[7]);
      int src0 = (g & 1) * 32 + q;
      int src1 = src0 + 16;
      unsigned a0 = (unsigned)__shfl((int)w00, src0);
      unsigned a1 = (unsigned)__shfl((int)w01, src0);
      unsigned c0 = (unsigned)__shfl((int)w10, src0);
      unsigned c1 = (unsigned)__shfl((int)w11, src0);
      unsigned d0 = (unsigned)__shfl((int)w00, src1);
      unsigned d1 = (unsigned)__shfl((int)w01, src1);
      unsigned e0 = (unsigned)__shfl((int)w10, src1);
      unsigned e1 = (unsigned)__shfl((int)w11, src1);
      int fsel = g >> 1;
      u32x4 pw;
      pw[0] = fsel ? c0 : a0;
      pw[1] = fsel ? c1 : a1;
      pw[2] = fsel ? e0 : d0;
      pw[3] = fsel ? e1 : d1;
      bf16x8 pfrag = __builtin_bit_cast(bf16x8, pw);

      __builtin_amdgcn_s_setprio(1);
#pragma unroll
      for (int df = 0; df < 4; df++) {
        bf16x8 vf = *(const bf16x8*)(Vc + (df * 16 + q) * 128 + ((ks32 * 64 + g * 16) ^ sw));
        acc[df] = __builtin_amdgcn_mfma_f32_16x16x32_bf16(vf, pfrag, acc[df], 0, 0, 0);
      }
      __builtin_amdgcn_s_setprio(0);
    }
    __syncthreads();
    cur ^= 1;
  }

  const int row = bh * 1024 + qt * 16 + q;
  float* Op = Opart + ((size_t)ks * 16384 + row) * 64 + g * 4;
#pragma unroll
  for (int df = 0; df < 4; df++) *(f32x4*)(Op + df * 16) = acc[df];
  if (g == 0) ml[(size_t)ks * 16384 + row] = make_float2(mrun, lsum);
}

// ---------------------------------------------------------------------------
// Combine 4 k-split partials -> normalized bf16 attention output (row-major)
__global__ __launch_bounds__(256)
void attn_combine_kernel(const float* __restrict__ Opart, const float2* __restrict__ ml,
                         short* __restrict__ attnb) {
  const int qt = blockIdx.x;
  const int bh = blockIdx.y;
  const int q = threadIdx.x >> 4, dq = threadIdx.x & 15;
  const int row = bh * 1024 + qt * 16 + q;
  float2 m0 = ml[row];
  float2 m1 = ml[16384 + row];
  float2 m2 = ml[2 * 16384 + row];
  float2 m3 = ml[3 * 16384 + row];
  float M = fmaxf(fmaxf(m0.x, m1.x), fmaxf(m2.x, m3.x));
  float e0 = __expf(m0.x - M), e1 = __expf(m1.x - M);
  float e2 = __expf(m2.x - M), e3 = __expf(m3.x - M);
  float inv = 1.0f / (m0.y * e0 + m1.y * e1 + m2.y * e2 + m3.y * e3);
  const size_t base = (size_t)row * 64 + dq * 4;
  f32x4 a0 = *(const f32x4*)(Opart + base);
  f32x4 a1 = *(const f32x4*)(Opart + (size_t)16384 * 64 + base);
  f32x4 a2 = *(const f32x4*)(Opart + (size_t)2 * 16384 * 64 + base);
  f32x4 a3 = *(const f32x4*)(Opart + (size_t)3 * 16384 * 64 + base);
  bf16x4 oo;
#pragma unroll
  for (int j = 0; j < 4; j++)
    oo[j] = f2bf((a0[j] * e0 + a1[j] * e1 + a2[j] * e2 + a3[j] * e3) * inv);
  const int b = bh >> 3, h = bh & 7;
  *(bf16x4*)(attnb + ((size_t)b * 1024 + qt * 16 + q) * 512 + h * 64 + dq * 4) = oo;
}

// ---------------------------------------------------------------------------
extern "C" void kernel_launch(void* const* d_in, const int* in_sizes, int n_in,
                              void* d_out, int out_size, void* d_ws, size_t ws_size,
                              hipStream_t stream) {
  const int D = 512, F = 2048;
  const int Mq = 2048, Mkv = 8192;

  char* ws = (char*)d_ws;
  size_t off = 0;
  auto alloc = [&](size_t bytes) { char* p = ws + off; off += (bytes + 255) & ~(size_t)255; return p; };
  float* x    = (float*)alloc((size_t)Mq * D * 4);
  short* qln  = (short*)alloc((size_t)Mq * D * 2);
  short* kvK  = (short*)alloc((size_t)Mkv * D * 2);
  short* kvV  = (short*)alloc((size_t)Mkv * D * 2);
  short* Qb   = (short*)alloc((size_t)Mq * D * 2);
  short* Kb   = (short*)alloc((size_t)Mkv * D * 2);
  short* Vt   = (short*)alloc((size_t)Mkv * D * 2);
  short* attnb= (short*)alloc((size_t)Mq * D * 2);
  char*  big  = alloc((size_t)4 * 16384 * 64 * 4);
  float* Opart = (float*)big;
  short* hffn  = (short*)big;
  float2* mlb = (float2*)alloc((size_t)4 * 16384 * 8);
  short* WT[8];
  for (int i = 0; i < 8; i++) WT[i] = (short*)alloc((size_t)D * D * 2);
  short* w1T = (short*)alloc((size_t)D * F * 2);
  short* w2T = (short*)alloc((size_t)F * D * 2);

  Tc8 tc8;
  const int widx[8] = {6, 7, 8, 9, 16, 17, 18, 19};
  for (int i = 0; i < 8; i++) { tc8.src[i] = (const float*)d_in[widx[i]]; tc8.dst[i] = WT[i]; }
  tcast_tile8_kernel<<<dim3(8, 8, 8), 256, 0, stream>>>(tc8);
  tcast_tile_kernel<<<dim3(8, 32), 256, 0, stream>>>((const float*)d_in[26], w1T, 512, 2048);
  tcast_tile_kernel<<<dim3(32, 8), 256, 0, stream>>>((const float*)d_in[28], w2T, 2048, 512);

  float* out = (float*)d_out;
  hipMemcpyAsync(x, d_in[0], (size_t)Mq * D * 4, hipMemcpyDeviceToDevice, stream);
  hipMemcpyAsync(out + (size_t)Mq * D, d_in[2], (size_t)Mkv * D * 4, hipMemcpyDeviceToDevice, stream);
  hipMemcpyAsync(out + (size_t)Mq * D + (size_t)Mkv * D, d_in[4], (size_t)Mkv * D * 4,
                 hipMemcpyDeviceToDevice, stream);

  auto attn_sublayer = [&](int g_i, int b_i, int kv_i, int pe_i, int w0, int bq_i, int bk_i,
                           int bv_i, int bo_i) {
    ln_kernel<1><<<Mq / 4, 256, 0, stream>>>(x, (const float*)d_in[g_i], (const float*)d_in[b_i],
                                             (const float*)d_in[1], qln);
    addpe_kernel<<<(Mkv * D) / 1024, 256, 0, stream>>>((const float*)d_in[kv_i],
                                                       (const float*)d_in[pe_i], kvK, kvV);
    // Q proj: 2048x512x512, 64x64 tile -> 256 blocks
    gemm2_kernel<2, 2, 0, 0><<<dim3(Mq / 64, D / 64), 256, 0, stream>>>(
        qln, WT[w0], (const float*)d_in[bq_i], nullptr, Qb, Mq, D, D, D, D);
    // K proj: 8192x512x512, 128x64 tile -> 512 blocks
    gemm2_kernel<4, 2, 0, 0><<<dim3(Mkv / 128, D / 64), 256, 0, stream>>>(
        kvK, WT[w0 + 1], (const float*)d_in[bk_i], nullptr, Kb, Mkv, D, D, D, D);
    // V proj (transposed out): 8192x512x512
    gemm2_kernel<4, 2, 2, 0><<<dim3(Mkv / 128, D / 64), 256, 0, stream>>>(
        kvV, WT[w0 + 2], (const float*)d_in[bv_i], nullptr, Vt, Mkv, D, D, D, D);
    attn_kernel<<<1024, 256, 0, stream>>>(Qb, Kb, Vt, Opart, mlb);
    attn_combine_kernel<<<dim3(64, 16), 256, 0, stream>>>(Opart, mlb, attnb);
    // O proj + residual (f32 out): 2048x512x512
    gemm2_kernel<2, 2, 1, 0><<<dim3(Mq / 64, D / 64), 256, 0, stream>>>(
        attnb, WT[w0 + 3], (const float*)d_in[bo_i], x, x, Mq, D, D, D, D);
  };

  attn_sublayer(14, 15, 2, 3, 0, 10, 11, 12, 13);
  attn_sublayer(24, 25, 4, 5, 4, 20, 21, 22, 23);

  // FFN
  ln_kernel<0><<<Mq / 4, 256, 0, stream>>>(x, (const float*)d_in[30], (const float*)d_in[31],
                                           nullptr, qln);
  // FFN1: 2048x2048x512 + ReLU, 128x64 tile -> 512 blocks
  gemm2_kernel<4, 2, 0, 1><<<dim3(Mq / 128, F / 64), 256, 0, stream>>>(
      qln, w1T, (const float*)d_in[27], nullptr, hffn, Mq, F, D, D, D);
  // FFN2: 2048x512x2048 + residual (f32 out), 64x64 tile -> 256 blocks
  gemm2_kernel<2, 2, 1, 0><<<dim3(Mq / 64, D / 64), 256, 0, stream>>>(
      hffn, w2T, (const float*)d_in[29], x, out, Mq, D, F, F, F);
}

// Round 5
// 431.424 us; speedup vs baseline: 1.6710x; 1.0069x over previous
//
#include <hip/hip_runtime.h>

typedef __attribute__((ext_vector_type(8))) short bf16x8;
typedef __attribute__((ext_vector_type(4))) short bf16x4;
typedef __attribute__((ext_vector_type(4))) float f32x4;
typedef __attribute__((ext_vector_type(4))) unsigned int u32x4;

#define DEV static __device__ __forceinline__

DEV short f2bf(float f) {
  union { float f; unsigned u; } v; v.f = f;
  unsigned r = v.u + 0x7fffu + ((v.u >> 16) & 1u);
  return (short)(r >> 16);
}
DEV unsigned pack2(float lo, float hi) {
  return ((unsigned)(unsigned short)f2bf(hi) << 16) | (unsigned)(unsigned short)f2bf(lo);
}

DEV void gload16(const void* g, void* l) {
  __builtin_amdgcn_global_load_lds(
      (const __attribute__((address_space(1))) unsigned int*)g,
      (__attribute__((address_space(3))) unsigned int*)l, 16, 0, 0);
}

// ---------------------------------------------------------------------------
// Coalesced weight cast+transpose via 64x64 LDS tile: Wt[n*K+k] = bf16(W[k*N+n])
DEV void ttile(const float* __restrict__ W, short* __restrict__ Wt, int K, int N,
               int k0, int n0, float (*t)[65], int tid) {
  const int c = tid & 63, r4 = tid >> 6;
#pragma unroll
  for (int i = 0; i < 16; i++)
    t[i * 4 + r4][c] = W[(size_t)(k0 + i * 4 + r4) * N + n0 + c];
  __syncthreads();
#pragma unroll
  for (int i = 0; i < 16; i++)
    Wt[(size_t)(n0 + i * 4 + r4) * K + k0 + c] = f2bf(t[c][i * 4 + r4]);
}

struct Tc8 { const float* src[8]; short* dst[8]; };

__global__ __launch_bounds__(256)
void tcast_tile8_kernel(Tc8 a) {
  __shared__ float t[64][65];
  ttile(a.src[blockIdx.z], a.dst[blockIdx.z], 512, 512,
        blockIdx.x * 64, blockIdx.y * 64, t, threadIdx.x);
}

__global__ __launch_bounds__(256)
void tcast_tile_kernel(const float* __restrict__ W, short* __restrict__ Wt, int K, int N) {
  __shared__ float t[64][65];
  ttile(W, Wt, K, N, blockIdx.x * 64, blockIdx.y * 64, t, threadIdx.x);
}

// ---------------------------------------------------------------------------
// kvK = bf16(a+pe), kvV = bf16(a); 4 elems/thread
__global__ __launch_bounds__(256)
void addpe_kernel(const float* __restrict__ a, const float* __restrict__ p,
                  short* __restrict__ outK, short* __restrict__ outV) {
  size_t i = (size_t)(blockIdx.x * 256 + threadIdx.x) * 4;
  f32x4 va = *(const f32x4*)(a + i);
  f32x4 vp = *(const f32x4*)(p + i);
  bf16x4 k, v;
#pragma unroll
  for (int j = 0; j < 4; j++) { k[j] = f2bf(va[j] + vp[j]); v[j] = f2bf(va[j]); }
  *(bf16x4*)(outK + i) = k;
  *(bf16x4*)(outV + i) = v;
}

// ---------------------------------------------------------------------------
// LayerNorm over D=512, one wave per row, optional +pe, bf16 out
template<int PE>
__global__ __launch_bounds__(256)
void ln_kernel(const float* __restrict__ X, const float* __restrict__ gamma,
               const float* __restrict__ beta, const float* __restrict__ pe,
               short* __restrict__ Y) {
  const int wave = threadIdx.x >> 6, lane = threadIdx.x & 63;
  const int row = blockIdx.x * 4 + wave;
  const float* x = X + (size_t)row * 512 + lane * 8;
  f32x4 v0 = *(const f32x4*)x;
  f32x4 v1 = *(const f32x4*)(x + 4);
  float s = ((v0[0] + v0[1]) + (v0[2] + v0[3])) + ((v1[0] + v1[1]) + (v1[2] + v1[3]));
#pragma unroll
  for (int m = 1; m < 64; m <<= 1) s += __shfl_xor(s, m);
  float mu = s * (1.0f / 512.0f);
  float vs = 0.0f;
#pragma unroll
  for (int j = 0; j < 4; j++) { float d = v0[j] - mu; vs += d * d; }
#pragma unroll
  for (int j = 0; j < 4; j++) { float d = v1[j] - mu; vs += d * d; }
#pragma unroll
  for (int m = 1; m < 64; m <<= 1) vs += __shfl_xor(vs, m);
  float rstd = rsqrtf(vs * (1.0f / 512.0f) + 1e-6f);
  const int c = lane * 8;
  f32x4 g0 = *(const f32x4*)(gamma + c);
  f32x4 g1 = *(const f32x4*)(gamma + c + 4);
  f32x4 b0 = *(const f32x4*)(beta + c);
  f32x4 b1 = *(const f32x4*)(beta + c + 4);
  f32x4 p0 = {0,0,0,0}, p1 = {0,0,0,0};
  if (PE) {
    p0 = *(const f32x4*)(pe + (size_t)row * 512 + c);
    p1 = *(const f32x4*)(pe + (size_t)row * 512 + c + 4);
  }
  bf16x8 out;
#pragma unroll
  for (int j = 0; j < 4; j++) out[j]     = f2bf((v0[j] - mu) * rstd * g0[j] + b0[j] + p0[j]);
#pragma unroll
  for (int j = 0; j < 4; j++) out[4 + j] = f2bf((v1[j] - mu) * rstd * g1[j] + b1[j] + p1[j]);
  *(bf16x8*)(Y + (size_t)row * 512 + c) = out;
}

// ---------------------------------------------------------------------------
// GEMM v3 (m97 structure): LDS-staged, double-buffered, XOR-swizzled.
// Tile BM=32*FM x BN=32*FN, 4 waves (2x2). MERGE=1: rows >= M/2 use Bt1/bias1.
// OUTMODE: 0 = bf16 row-major, 1 = f32 row-major + residual, 2 = bf16 V-transposed
template<int FM, int FN, int OUTMODE, int RELU, int MERGE>
__global__ __launch_bounds__(256)
void gemm3_kernel(const short* __restrict__ A, const short* __restrict__ Bt0,
                  const short* __restrict__ Bt1, const float* __restrict__ bias0,
                  const float* __restrict__ bias1, const float* __restrict__ res,
                  void* __restrict__ Cv, int M, int N, int Klen, int lda, int ldb) {
  constexpr int BM = 32 * FM, BN = 32 * FN;
  __shared__ alignas(16) short As[2][BM * 32];
  __shared__ alignas(16) short Bs[2][BN * 32];
  const int tid = threadIdx.x;
  const int lane = tid & 63, w = tid >> 6;
  const int g = lane >> 4, x15 = lane & 15;
  const int wm = w >> 1, wn = w & 1;
  const int Mb = blockIdx.x * BM, Nb = blockIdx.y * BN;
  const short* Bt = (MERGE && Mb >= (M >> 1)) ? Bt1 : Bt0;
  const float* bias = (MERGE && Mb >= (M >> 1)) ? bias1 : bias0;
  const short* Ag = A + (size_t)Mb * lda;
  const short* Bg = Bt + (size_t)Nb * ldb;

  auto stage = [&](int kb, int cur) {
    const int c = tid & 3, rr = tid >> 2;
#pragma unroll
    for (int j = 0; j < BM / 64; j++) {
      int row = j * 64 + rr;
      gload16(Ag + (size_t)row * lda + kb + ((c ^ (row & 3)) << 3),
              &As[cur][j * 2048 + tid * 8]);
    }
#pragma unroll
    for (int j = 0; j < BN / 64; j++) {
      int row = j * 64 + rr;
      gload16(Bg + (size_t)row * ldb + kb + ((c ^ (row & 3)) << 3),
              &Bs[cur][j * 2048 + tid * 8]);
    }
  };

  f32x4 acc[FM][FN] = {};
  const int nt = Klen >> 5;
  stage(0, 0);
  __syncthreads();
  int cur = 0;
  for (int t = 0; t < nt; t++) {
    if (t + 1 < nt) stage((t + 1) << 5, cur ^ 1);
    const char* Ac = (const char*)&As[cur][0];
    const char* Bc = (const char*)&Bs[cur][0];
    const int swr = (g ^ (x15 & 3)) << 4;
    bf16x8 af[FM], bfr[FN];
#pragma unroll
    for (int fm = 0; fm < FM; fm++)
      af[fm] = *(const bf16x8*)(Ac + (wm * (BM / 2) + fm * 16 + x15) * 64 + swr);
#pragma unroll
    for (int fn = 0; fn < FN; fn++)
      bfr[fn] = *(const bf16x8*)(Bc + (wn * (BN / 2) + fn * 16 + x15) * 64 + swr);
    __builtin_amdgcn_s_setprio(1);
#pragma unroll
    for (int fm = 0; fm < FM; fm++)
#pragma unroll
      for (int fn = 0; fn < FN; fn++)
        acc[fm][fn] = __builtin_amdgcn_mfma_f32_16x16x32_bf16(af[fm], bfr[fn], acc[fm][fn], 0, 0, 0);
    __builtin_amdgcn_s_setprio(0);
    __syncthreads();
    cur ^= 1;
  }

#pragma unroll
  for (int fm = 0; fm < FM; fm++)
#pragma unroll
    for (int fn = 0; fn < FN; fn++) {
      int n = Nb + wn * (BN / 2) + fn * 16 + x15;
      float bs = bias[n];
      int m0 = Mb + wm * (BM / 2) + fm * 16 + g * 4;
      if (OUTMODE == 2) {
        int bh = ((m0 >> 12) << 3) + (n >> 6);
        bf16x4 ov;
#pragma unroll
        for (int r = 0; r < 4; r++) ov[r] = f2bf(acc[fm][fn][r] + bs);
        *(bf16x4*)((short*)Cv + ((size_t)bh * 64 + (n & 63)) * 4096 + (m0 & 4095)) = ov;
      } else {
#pragma unroll
        for (int r = 0; r < 4; r++) {
          int m = m0 + r;
          float v = acc[fm][fn][r] + bs;
          if (RELU) v = fmaxf(v, 0.0f);
          if (OUTMODE == 1) {
            ((float*)Cv)[(size_t)m * N + n] = res[(size_t)m * N + n] + v;
          } else {
            ((short*)Cv)[(size_t)m * N + n] = f2bf(v);
          }
        }
      }
    }
}

// ---------------------------------------------------------------------------
// Flash attention v4: k-split x8, 4-wave blocks sharing LDS K/V tiles.
// Block = (ks, bh, qtg): wave w handles q-tile qtg*4+w; keys [ks*512, ks*512+512).
__global__ __launch_bounds__(256, 4)
void attn_kernel(const short* __restrict__ Q, const short* __restrict__ K,
                 const short* __restrict__ Vt, float* __restrict__ Opart,
                 float2* __restrict__ ml) {
  __shared__ alignas(16) short Kl[2][4096];
  __shared__ alignas(16) short Vl[2][4096];

  const int tid = threadIdx.x;
  const int lane = tid & 63, w = tid >> 6;
  const int g = lane >> 4, q = lane & 15;
  // XCD-bijective swizzle: 2048 blocks, 8 XCDs, 256 per XCD; one ks per XCD chunk
  const int o = ((blockIdx.x & 7) << 8) + (blockIdx.x >> 3);
  const int ks = o >> 8, bh = (o >> 4) & 15, qtg = o & 15;
  const int b = bh >> 3, h = bh & 7;
  const int qt = qtg * 4 + w;

  const char* Kg = (const char*)K + ((size_t)b * 4096 * 512 + h * 64) * 2;
  const char* Vg = (const char*)Vt + ((size_t)bh * 64 * 4096) * 2;
  const int swz = (((lane & 7) ^ (lane >> 3)) << 4);
  const int sw = (q & 7) << 4;

  const short* Qp = Q + ((size_t)b * 1024 + qt * 16) * 512 + h * 64;
  bf16x8 qf0 = *(const bf16x8*)(Qp + (size_t)q * 512 + g * 8);
  bf16x8 qf1 = *(const bf16x8*)(Qp + (size_t)q * 512 + 32 + g * 8);

  f32x4 acc[4] = {{0,0,0,0},{0,0,0,0},{0,0,0,0},{0,0,0,0}};
  float mrun = -1e30f, lsum = 0.0f;
  const int k0 = ks * 512;
  const int r0 = w * 16;

  auto stage = [&](int kb, int cur) {
    const char* kg = Kg + (size_t)(kb + r0 + (lane >> 3)) * 1024 + swz;
    gload16(kg,            &Kl[cur][r0 * 64]);
    gload16(kg + 8 * 1024, &Kl[cur][(r0 + 8) * 64]);
    const char* vg = Vg + (size_t)(r0 + (lane >> 3)) * 8192 + (size_t)kb * 2 + swz;
    gload16(vg,            &Vl[cur][r0 * 64]);
    gload16(vg + 8 * 8192, &Vl[cur][(r0 + 8) * 64]);
  };

  stage(k0, 0);
  __syncthreads();
  int cur = 0;
  for (int t = 0; t < 8; t++) {
    if (t < 7) stage(k0 + (t + 1) * 64, cur ^ 1);
    const char* Kc = (const char*)&Kl[cur][0];
    const char* Vc = (const char*)&Vl[cur][0];
#pragma unroll
    for (int ks32 = 0; ks32 < 2; ks32++) {
      const char* Kb8 = Kc + ks32 * 4096;
      bf16x8 k00 = *(const bf16x8*)(Kb8 + q * 128        + ((g * 16) ^ sw));
      bf16x8 k01 = *(const bf16x8*)(Kb8 + q * 128        + ((64 + g * 16) ^ sw));
      bf16x8 k10 = *(const bf16x8*)(Kb8 + (q + 16) * 128 + ((g * 16) ^ sw));
      bf16x8 k11 = *(const bf16x8*)(Kb8 + (q + 16) * 128 + ((64 + g * 16) ^ sw));
      f32x4 s0 = {0,0,0,0}, s1 = {0,0,0,0};
      __builtin_amdgcn_s_setprio(1);
      s0 = __builtin_amdgcn_mfma_f32_16x16x32_bf16(k00, qf0, s0, 0, 0, 0);
      s0 = __builtin_amdgcn_mfma_f32_16x16x32_bf16(k01, qf1, s0, 0, 0, 0);
      s1 = __builtin_amdgcn_mfma_f32_16x16x32_bf16(k10, qf0, s1, 0, 0, 0);
      s1 = __builtin_amdgcn_mfma_f32_16x16x32_bf16(k11, qf1, s1, 0, 0, 0);
      __builtin_amdgcn_s_setprio(0);

      float sv[8];
      float tmax = -1e30f;
#pragma unroll
      for (int r = 0; r < 4; r++) { sv[r] = s0[r] * 0.125f; tmax = fmaxf(tmax, sv[r]); }
#pragma unroll
      for (int r = 0; r < 4; r++) { sv[4 + r] = s1[r] * 0.125f; tmax = fmaxf(tmax, sv[4 + r]); }
      tmax = fmaxf(tmax, __shfl_xor(tmax, 16));
      tmax = fmaxf(tmax, __shfl_xor(tmax, 32));

      if (__any(tmax > mrun + 6.0f)) {
        float mnew = fmaxf(mrun, tmax);
        float corr = __expf(mrun - mnew);
        lsum *= corr;
#pragma unroll
        for (int df = 0; df < 4; df++)
#pragma unroll
          for (int r = 0; r < 4; r++) acc[df][r] *= corr;
        mrun = mnew;
      }
      float p[8], psum = 0.0f;
#pragma unroll
      for (int i = 0; i < 8; i++) { p[i] = __expf(sv[i] - mrun); psum += p[i]; }
      psum += __shfl_xor(psum, 16);
      psum += __shfl_xor(psum, 32);
      lsum += psum;

      unsigned w00 = pack2(p[0], p[1]), w01 = pack2(p[2], p[3]);
      unsigned w10 = pack2(p[4], p[5]), w11 = pack2(p[6], p[7]);
      int src0 = (g & 1) * 32 + q;
      int src1 = src0 + 16;
      unsigned a0 = (unsigned)__shfl((int)w00, src0);
      unsigned a1 = (unsigned)__shfl((int)w01, src0);
      unsigned c0 = (unsigned)__shfl((int)w10, src0);
      unsigned c1 = (unsigned)__shfl((int)w11, src0);
      unsigned d0 = (unsigned)__shfl((int)w00, src1);
      unsigned d1 = (unsigned)__shfl((int)w01, src1);
      unsigned e0 = (unsigned)__shfl((int)w10, src1);
      unsigned e1 = (unsigned)__shfl((int)w11, src1);
      int fsel = g >> 1;
      u32x4 pw;
      pw[0] = fsel ? c0 : a0;
      pw[1] = fsel ? c1 : a1;
      pw[2] = fsel ? e0 : d0;
      pw[3] = fsel ? e1 : d1;
      bf16x8 pfrag = __builtin_bit_cast(bf16x8, pw);

      __builtin_amdgcn_s_setprio(1);
#pragma unroll
      for (int df = 0; df < 4; df++) {
        bf16x8 vf = *(const bf16x8*)(Vc + (df * 16 + q) * 128 + ((ks32 * 64 + g * 16) ^ sw));
        acc[df] = __builtin_amdgcn_mfma_f32_16x16x32_bf16(vf, pfrag, acc[df], 0, 0, 0);
      }
      __builtin_amdgcn_s_setprio(0);
    }
    __syncthreads();
    cur ^= 1;
  }

  const int row = bh * 1024 + qt * 16 + q;
  float* Op = Opart + ((size_t)ks * 16384 + row) * 64 + g * 4;
#pragma unroll
  for (int df = 0; df < 4; df++) *(f32x4*)(Op + df * 16) = acc[df];
  if (g == 0) ml[(size_t)ks * 16384 + row] = make_float2(mrun, lsum);
}

// ---------------------------------------------------------------------------
// Combine 8 k-split partials -> normalized bf16 attention output (row-major)
__global__ __launch_bounds__(256)
void attn_combine_kernel(const float* __restrict__ Opart, const float2* __restrict__ ml,
                         short* __restrict__ attnb) {
  const int qt = blockIdx.x;
  const int bh = blockIdx.y;
  const int q = threadIdx.x >> 4, dq = threadIdx.x & 15;
  const int row = bh * 1024 + qt * 16 + q;
  float2 mls[8];
  float M = -1e30f;
#pragma unroll
  for (int s = 0; s < 8; s++) { mls[s] = ml[(size_t)s * 16384 + row]; M = fmaxf(M, mls[s].x); }
  float es[8], den = 0.0f;
#pragma unroll
  for (int s = 0; s < 8; s++) { es[s] = __expf(mls[s].x - M); den += mls[s].y * es[s]; }
  float inv = 1.0f / den;
  const size_t base = (size_t)row * 64 + dq * 4;
  f32x4 accv = {0, 0, 0, 0};
#pragma unroll
  for (int s = 0; s < 8; s++) {
    f32x4 a = *(const f32x4*)(Opart + (size_t)s * 16384 * 64 + base);
#pragma unroll
    for (int j = 0; j < 4; j++) accv[j] += a[j] * es[s];
  }
  bf16x4 oo;
#pragma unroll
  for (int j = 0; j < 4; j++) oo[j] = f2bf(accv[j] * inv);
  const int b = bh >> 3, h = bh & 7;
  *(bf16x4*)(attnb + ((size_t)b * 1024 + qt * 16 + q) * 512 + h * 64 + dq * 4) = oo;
}

// ---------------------------------------------------------------------------
extern "C" void kernel_launch(void* const* d_in, const int* in_sizes, int n_in,
                              void* d_out, int out_size, void* d_ws, size_t ws_size,
                              hipStream_t stream) {
  const int D = 512, F = 2048;
  const int Mq = 2048, Mkv = 8192, Mkv2 = 16384;

  char* ws = (char*)d_ws;
  size_t off = 0;
  auto alloc = [&](size_t bytes) { char* p = ws + off; off += (bytes + 255) & ~(size_t)255; return p; };
  // 32MB region: [kvK_all 16MB | kvV_all 16MB], later aliased by Opart (32MB) and hffn (8MB).
  char* kvbase = alloc((size_t)32 * 1024 * 1024);
  short* kvK  = (short*)kvbase;
  short* kvV  = (short*)(kvbase + (size_t)Mkv2 * D * 2);
  float* Opart = (float*)kvbase;
  short* hffn  = (short*)kvbase;
  float* x    = (float*)alloc((size_t)Mq * D * 4);
  short* qln  = (short*)alloc((size_t)Mq * D * 2);
  short* Qb   = (short*)alloc((size_t)Mq * D * 2);
  short* Kb   = (short*)alloc((size_t)Mkv2 * D * 2);   // frame rows 0..8191, obj 8192..
  short* Vt   = (short*)alloc((size_t)Mkv2 * D * 2);   // [32][64][4096] bf16
  short* attnb= (short*)alloc((size_t)Mq * D * 2);
  float2* mlb = (float2*)alloc((size_t)8 * 16384 * 8);
  short* WT[8];
  for (int i = 0; i < 8; i++) WT[i] = (short*)alloc((size_t)D * D * 2);
  short* w1T = (short*)alloc((size_t)D * F * 2);
  short* w2T = (short*)alloc((size_t)F * D * 2);

  Tc8 tc8;
  const int widx[8] = {6, 7, 8, 9, 16, 17, 18, 19};
  for (int i = 0; i < 8; i++) { tc8.src[i] = (const float*)d_in[widx[i]]; tc8.dst[i] = WT[i]; }
  tcast_tile8_kernel<<<dim3(8, 8, 8), 256, 0, stream>>>(tc8);
  tcast_tile_kernel<<<dim3(8, 32), 256, 0, stream>>>((const float*)d_in[26], w1T, 512, 2048);
  tcast_tile_kernel<<<dim3(32, 8), 256, 0, stream>>>((const float*)d_in[28], w2T, 2048, 512);

  float* out = (float*)d_out;
  hipMemcpyAsync(x, d_in[0], (size_t)Mq * D * 4, hipMemcpyDeviceToDevice, stream);
  hipMemcpyAsync(out + (size_t)Mq * D, d_in[2], (size_t)Mkv * D * 4, hipMemcpyDeviceToDevice, stream);
  hipMemcpyAsync(out + (size_t)Mq * D + (size_t)Mkv * D, d_in[4], (size_t)Mkv * D * 4,
                 hipMemcpyDeviceToDevice, stream);

  // KV add-PE + cast (both sublayers upfront)
  addpe_kernel<<<(Mkv * D) / 1024, 256, 0, stream>>>((const float*)d_in[2], (const float*)d_in[3],
                                                     kvK, kvV);
  addpe_kernel<<<(Mkv * D) / 1024, 256, 0, stream>>>((const float*)d_in[4], (const float*)d_in[5],
                                                     kvK + (size_t)Mkv * D, kvV + (size_t)Mkv * D);
  // Merged K projection: rows 0..8191 with f_Wk, 8192..16383 with o_Wk
  gemm3_kernel<4, 4, 0, 0, 1><<<dim3(Mkv2 / 128, D / 128), 256, 0, stream>>>(
      kvK, WT[1], WT[5], (const float*)d_in[11], (const float*)d_in[21], nullptr,
      Kb, Mkv2, D, D, D, D);
  // Merged V projection (transposed out)
  gemm3_kernel<4, 4, 2, 0, 1><<<dim3(Mkv2 / 128, D / 128), 256, 0, stream>>>(
      kvV, WT[2], WT[6], (const float*)d_in[12], (const float*)d_in[22], nullptr,
      Vt, Mkv2, D, D, D, D);

  auto attn_sublayer = [&](int g_i, int b_i, int w0, int bq_i, int bo_i, int half) {
    ln_kernel<1><<<Mq / 4, 256, 0, stream>>>(x, (const float*)d_in[g_i], (const float*)d_in[b_i],
                                             (const float*)d_in[1], qln);
    gemm3_kernel<2, 2, 0, 0, 0><<<dim3(Mq / 64, D / 64), 256, 0, stream>>>(
        qln, WT[w0], nullptr, (const float*)d_in[bq_i], nullptr, nullptr, Qb, Mq, D, D, D, D);
    attn_kernel<<<2048, 256, 0, stream>>>(Qb, Kb + (size_t)half * Mkv * D,
                                          Vt + (size_t)half * 16 * 64 * 4096, Opart, mlb);
    attn_combine_kernel<<<dim3(64, 16), 256, 0, stream>>>(Opart, mlb, attnb);
    gemm3_kernel<2, 2, 1, 0, 0><<<dim3(Mq / 64, D / 64), 256, 0, stream>>>(
        attnb, WT[w0 + 3], nullptr, (const float*)d_in[bo_i], nullptr, x, x, Mq, D, D, D, D);
  };

  attn_sublayer(14, 15, 0, 10, 13, 0);   // frame
  attn_sublayer(24, 25, 4, 20, 23, 1);   // obj

  // FFN
  ln_kernel<0><<<Mq / 4, 256, 0, stream>>>(x, (const float*)d_in[30], (const float*)d_in[31],
                                           nullptr, qln);
  gemm3_kernel<4, 4, 0, 1, 0><<<dim3(Mq / 128, F / 128), 256, 0, stream>>>(
      qln, w1T, nullptr, (const float*)d_in[27], nullptr, nullptr, hffn, Mq, F, D, D, D);
  gemm3_kernel<2, 2, 1, 0, 0><<<dim3(Mq / 64, D / 64), 256, 0, stream>>>(
      hffn, w2T, nullptr, (const float*)d_in[29], nullptr, x, out, Mq, D, F, F, F);
}